// Round 1
// baseline (1258.333 us; speedup 1.0000x reference)
//
#include <hip/hip_runtime.h>
#include <hip/hip_bf16.h>
#include <math.h>

// Problem constants (fixed by the reference)
#define NINP 512
#define NOUT 256
#define NH   3
#define HD   768   // NH*NOUT

// ---------------------------------------------------------------------------
// Generic fp32 tiled GEMM: C[M,N] = A[M,K] @ B[K,N] (+ bias[N]).
// N must be a multiple of 128 (grid.x = N/128); K must be a multiple of 16.
// M is guarded (row clamp on loads, guard on stores).
// 128x128 tile, 256 threads, 8x8 micro-tile per thread, BK=16.
// ---------------------------------------------------------------------------
__global__ __launch_bounds__(256)
void sgemm128(const float* __restrict__ A, int lda,
              const float* __restrict__ B, int ldb,
              const float* __restrict__ bias,
              float* __restrict__ C, int ldc,
              int M, int K)
{
    __shared__ float As[16][128];   // transposed A tile: As[k][m]
    __shared__ float Bs[16][128];   // Bs[k][n]

    const int tid = threadIdx.x;
    const int tx  = tid & 15;       // col group (0..15)
    const int ty  = tid >> 4;       // row group (0..15)
    const int row0 = blockIdx.y * 128;
    const int col0 = blockIdx.x * 128;

    float acc[8][8];
#pragma unroll
    for (int i = 0; i < 8; i++)
#pragma unroll
        for (int j = 0; j < 8; j++) acc[i][j] = 0.0f;

    for (int k0 = 0; k0 < K; k0 += 16) {
        // --- stage A tile (128 rows x 16 cols) ---
#pragma unroll
        for (int l = 0; l < 2; l++) {
            int id = tid * 2 + l;            // 0..511 float4 slots
            int ar = id >> 2;                // row 0..127
            int ac = (id & 3) << 2;          // col 0,4,8,12
            int gr = row0 + ar; if (gr >= M) gr = M - 1;   // clamp (stores guarded)
            const float4 v = *(const float4*)(A + (size_t)gr * lda + k0 + ac);
            As[ac + 0][ar] = v.x; As[ac + 1][ar] = v.y;
            As[ac + 2][ar] = v.z; As[ac + 3][ar] = v.w;
        }
        // --- stage B tile (16 rows x 128 cols) ---
#pragma unroll
        for (int l = 0; l < 2; l++) {
            int id = tid * 2 + l;
            int br = id >> 5;                // row 0..15
            int bc = (id & 31) << 2;         // col 0..124
            const float4 v = *(const float4*)(B + (size_t)(k0 + br) * ldb + col0 + bc);
            *(float4*)&Bs[br][bc] = v;
        }
        __syncthreads();

#pragma unroll
        for (int kk = 0; kk < 16; kk++) {
            float a[8], b[8];
            *(float4*)&a[0] = *(const float4*)&As[kk][ty * 8];
            *(float4*)&a[4] = *(const float4*)&As[kk][ty * 8 + 4];
            *(float4*)&b[0] = *(const float4*)&Bs[kk][tx * 8];
            *(float4*)&b[4] = *(const float4*)&Bs[kk][tx * 8 + 4];
#pragma unroll
            for (int i = 0; i < 8; i++)
#pragma unroll
                for (int j = 0; j < 8; j++)
                    acc[i][j] = fmaf(a[i], b[j], acc[i][j]);
        }
        __syncthreads();
    }

#pragma unroll
    for (int i = 0; i < 8; i++) {
        int r = row0 + ty * 8 + i;
        if (r < M) {
#pragma unroll
            for (int j = 0; j < 8; j += 4) {
                int c = col0 + tx * 8 + j;
                float4 v;
                v.x = acc[i][j + 0] + (bias ? bias[c + 0] : 0.0f);
                v.y = acc[i][j + 1] + (bias ? bias[c + 1] : 0.0f);
                v.z = acc[i][j + 2] + (bias ? bias[c + 2] : 0.0f);
                v.w = acc[i][j + 3] + (bias ? bias[c + 3] : 0.0f);
                *(float4*)(C + (size_t)r * ldc + c) = v;
            }
        }
    }
}

// ---------------------------------------------------------------------------
// Wl[k,h] = sum_d Wsrc[k, h*256+d] * attn_l[h,d]   (same for Wr/Wdst/attn_r)
// ---------------------------------------------------------------------------
__global__ void make_wlr(const float* __restrict__ Wsrc, const float* __restrict__ Wdst,
                         const float* __restrict__ attn_l, const float* __restrict__ attn_r,
                         float* __restrict__ Wl, float* __restrict__ Wr)
{
    int t = blockIdx.x * blockDim.x + threadIdx.x;
    if (t >= 2 * NINP * NH) return;
    int which = (t >= NINP * NH) ? 1 : 0;
    int i = t - which * NINP * NH;
    int k = i / NH, h = i % NH;
    const float* W  = which ? Wdst  : Wsrc;
    const float* av = which ? attn_r : attn_l;
    float s = 0.0f;
    for (int d = 0; d < NOUT; d++)
        s = fmaf(W[(size_t)k * HD + h * NOUT + d], av[h * NOUT + d], s);
    (which ? Wr : Wl)[k * NH + h] = s;
}

// bias2[j] = bhead[j] + sum_i gat_bias[i] * Whead[i,j]
__global__ void make_bias2(const float* __restrict__ gat_bias,
                           const float* __restrict__ Whead,
                           const float* __restrict__ bhead,
                           float* __restrict__ bias2)
{
    int j = threadIdx.x;   // 256 threads
    float s = bhead[j];
    for (int i = 0; i < HD; i++)
        s = fmaf(gat_bias[i], Whead[(size_t)i * NOUT + j], s);
    bias2[j] = s;
}

// ---------------------------------------------------------------------------
// el/er: out[n,h] = sum_k x[n,k] * Wv[k,h].   One wave per node.
// ---------------------------------------------------------------------------
__global__ __launch_bounds__(256)
void node_attn(const float* __restrict__ x, const float* __restrict__ Wv,
               float* __restrict__ out, int M)
{
    int node = blockIdx.x * 4 + (threadIdx.x >> 6);
    int lane = threadIdx.x & 63;
    if (node >= M) return;
    const float* xr = x + (size_t)node * NINP;
    float s0 = 0.f, s1 = 0.f, s2 = 0.f;
#pragma unroll
    for (int half = 0; half < 2; half++) {
        int k = half * 256 + lane * 4;
        float4 v = *(const float4*)(xr + k);
#pragma unroll
        for (int j = 0; j < 4; j++) {
            float xv = (&v.x)[j];
            const float* w = Wv + (size_t)(k + j) * NH;
            s0 = fmaf(xv, w[0], s0);
            s1 = fmaf(xv, w[1], s1);
            s2 = fmaf(xv, w[2], s2);
        }
    }
    for (int o = 32; o > 0; o >>= 1) {
        s0 += __shfl_xor(s0, o);
        s1 += __shfl_xor(s1, o);
        s2 += __shfl_xor(s2, o);
    }
    if (lane == 0) {
        out[node * NH + 0] = s0;
        out[node * NH + 1] = s1;
        out[node * NH + 2] = s2;
    }
}

// ---------------------------------------------------------------------------
// CSR build
// ---------------------------------------------------------------------------
__global__ void count_deg(const int* __restrict__ dst, int* __restrict__ cnt, int E)
{
    int t = blockIdx.x * blockDim.x + threadIdx.x;
    if (t < E) atomicAdd(&cnt[dst[t]], 1);
}

__global__ __launch_bounds__(1024)
void scan_deg(const int* __restrict__ cnt, int* __restrict__ rowptr,
              int* __restrict__ cursor, int n)
{
    __shared__ int tmp[1024];
    __shared__ int s_carry;
    int tid = threadIdx.x;
    if (tid == 0) { rowptr[0] = 0; s_carry = 0; }
    __syncthreads();
    for (int base = 0; base < n; base += 1024) {
        int i = base + tid;
        int v = (i < n) ? cnt[i] : 0;
        tmp[tid] = v;
        __syncthreads();
        for (int off = 1; off < 1024; off <<= 1) {
            int add = (tid >= off) ? tmp[tid - off] : 0;
            __syncthreads();
            tmp[tid] += add;
            __syncthreads();
        }
        int carry = s_carry;
        if (i < n) {
            int incl = carry + tmp[tid];
            rowptr[i + 1] = incl;
            cursor[i] = incl - v;     // exclusive prefix = segment start
        }
        __syncthreads();
        if (tid == 1023) s_carry = carry + tmp[1023];
        __syncthreads();
    }
}

__global__ void fill_csr(const int* __restrict__ dst, int* __restrict__ cursor,
                         int* __restrict__ eidx, int E)
{
    int t = blockIdx.x * blockDim.x + threadIdx.x;
    if (t < E) {
        int p = atomicAdd(&cursor[dst[t]], 1);
        eidx[p] = t;
    }
}

// ---------------------------------------------------------------------------
// Per-dst-node edge softmax + aggregation:
//   agg[n,h,k] = sum_{e: dst=n} alpha[e,h] * x_api[src[e], k]
// One block (256 threads) per dst node. Each thread owns 2 k-columns x 3 heads.
// ---------------------------------------------------------------------------
#define MAXC 256
__global__ __launch_bounds__(256)
void gat_agg(const int* __restrict__ rowptr, const int* __restrict__ eidx,
             const int* __restrict__ src,
             const float* __restrict__ el, const float* __restrict__ er,
             const float* __restrict__ x, float* __restrict__ agg)
{
    int n = blockIdx.x;
    int t = threadIdx.x;
    int beg = rowptr[n], end = rowptr[n + 1];
    int deg = end - beg;

    __shared__ float s_red[4][3];
    __shared__ float s_alpha[MAXC][3];
    __shared__ int   s_src[MAXC];

    float a00 = 0.f, a01 = 0.f, a10 = 0.f, a11 = 0.f, a20 = 0.f, a21 = 0.f;

    if (deg > 0) {
        const float er0 = er[n * NH + 0], er1 = er[n * NH + 1], er2 = er[n * NH + 2];

        // ---- pass 1: per-head max ----
        float m0 = -1e30f, m1 = -1e30f, m2 = -1e30f;
        for (int i = t; i < deg; i += 256) {
            int e = eidx[beg + i]; int s = src[e];
            float v0 = el[s * NH + 0] + er0; v0 = v0 > 0.f ? v0 : 0.2f * v0;
            float v1 = el[s * NH + 1] + er1; v1 = v1 > 0.f ? v1 : 0.2f * v1;
            float v2 = el[s * NH + 2] + er2; v2 = v2 > 0.f ? v2 : 0.2f * v2;
            m0 = fmaxf(m0, v0); m1 = fmaxf(m1, v1); m2 = fmaxf(m2, v2);
        }
        for (int o = 32; o > 0; o >>= 1) {
            m0 = fmaxf(m0, __shfl_xor(m0, o));
            m1 = fmaxf(m1, __shfl_xor(m1, o));
            m2 = fmaxf(m2, __shfl_xor(m2, o));
        }
        if ((t & 63) == 0) { int w = t >> 6; s_red[w][0] = m0; s_red[w][1] = m1; s_red[w][2] = m2; }
        __syncthreads();
        m0 = fmaxf(fmaxf(s_red[0][0], s_red[1][0]), fmaxf(s_red[2][0], s_red[3][0]));
        m1 = fmaxf(fmaxf(s_red[0][1], s_red[1][1]), fmaxf(s_red[2][1], s_red[3][1]));
        m2 = fmaxf(fmaxf(s_red[0][2], s_red[1][2]), fmaxf(s_red[2][2], s_red[3][2]));
        __syncthreads();

        // ---- pass 2: per-head sum of exp ----
        float z0 = 0.f, z1 = 0.f, z2 = 0.f;
        for (int i = t; i < deg; i += 256) {
            int e = eidx[beg + i]; int s = src[e];
            float v0 = el[s * NH + 0] + er0; v0 = v0 > 0.f ? v0 : 0.2f * v0;
            float v1 = el[s * NH + 1] + er1; v1 = v1 > 0.f ? v1 : 0.2f * v1;
            float v2 = el[s * NH + 2] + er2; v2 = v2 > 0.f ? v2 : 0.2f * v2;
            z0 += expf(v0 - m0); z1 += expf(v1 - m1); z2 += expf(v2 - m2);
        }
        for (int o = 32; o > 0; o >>= 1) {
            z0 += __shfl_xor(z0, o); z1 += __shfl_xor(z1, o); z2 += __shfl_xor(z2, o);
        }
        if ((t & 63) == 0) { int w = t >> 6; s_red[w][0] = z0; s_red[w][1] = z1; s_red[w][2] = z2; }
        __syncthreads();
        z0 = s_red[0][0] + s_red[1][0] + s_red[2][0] + s_red[3][0];
        z1 = s_red[0][1] + s_red[1][1] + s_red[2][1] + s_red[3][1];
        z2 = s_red[0][2] + s_red[1][2] + s_red[2][2] + s_red[3][2];
        __syncthreads();
        const float inv0 = 1.0f / z0, inv1 = 1.0f / z1, inv2 = 1.0f / z2;

        // ---- pass 3: alpha + aggregate, in chunks of MAXC edges ----
        for (int base = 0; base < deg; base += MAXC) {
            int cn = min(MAXC, deg - base);
            for (int i = t; i < cn; i += 256) {
                int e = eidx[beg + base + i]; int s = src[e];
                float v0 = el[s * NH + 0] + er0; v0 = v0 > 0.f ? v0 : 0.2f * v0;
                float v1 = el[s * NH + 1] + er1; v1 = v1 > 0.f ? v1 : 0.2f * v1;
                float v2 = el[s * NH + 2] + er2; v2 = v2 > 0.f ? v2 : 0.2f * v2;
                s_alpha[i][0] = expf(v0 - m0) * inv0;
                s_alpha[i][1] = expf(v1 - m1) * inv1;
                s_alpha[i][2] = expf(v2 - m2) * inv2;
                s_src[i] = s;
            }
            __syncthreads();
            for (int i = 0; i < cn; i++) {
                int s = s_src[i];
                float c0 = s_alpha[i][0], c1 = s_alpha[i][1], c2 = s_alpha[i][2];
                float2 xv = *(const float2*)(x + (size_t)s * NINP + 2 * t);
                a00 = fmaf(c0, xv.x, a00); a01 = fmaf(c0, xv.y, a01);
                a10 = fmaf(c1, xv.x, a10); a11 = fmaf(c1, xv.y, a11);
                a20 = fmaf(c2, xv.x, a20); a21 = fmaf(c2, xv.y, a21);
            }
            __syncthreads();
        }
    }

    size_t b = (size_t)n * (NH * NINP) + 2 * t;
    *(float2*)(agg + b)              = make_float2(a00, a01);
    *(float2*)(agg + b + NINP)       = make_float2(a10, a11);
    *(float2*)(agg + b + 2 * NINP)   = make_float2(a20, a21);
}

// ---------------------------------------------------------------------------
extern "C" void kernel_launch(void* const* d_in, const int* in_sizes, int n_in,
                              void* d_out, int out_size, void* d_ws, size_t ws_size,
                              hipStream_t stream)
{
    const float* emb_api  = (const float*)d_in[0];
    const float* emb_file = (const float*)d_in[1];
    // d_in[2] (e_tensor) is unused by the reference
    const int*   src      = (const int*)d_in[3];
    const int*   dst      = (const int*)d_in[4];
    const float* Wapi     = (const float*)d_in[5];
    const float* bapi     = (const float*)d_in[6];
    const float* Wfile    = (const float*)d_in[7];
    const float* bfile    = (const float*)d_in[8];
    const float* Wsrc     = (const float*)d_in[9];
    const float* Wdst     = (const float*)d_in[10];
    const float* attn_l   = (const float*)d_in[11];
    const float* attn_r   = (const float*)d_in[12];
    const float* gat_bias = (const float*)d_in[13];
    const float* Whead    = (const float*)d_in[14];
    const float* bhead    = (const float*)d_in[15];

    const int n_api  = in_sizes[0] / NINP;
    const int n_file = in_sizes[1] / NINP;
    const int E      = in_sizes[2];

    // ---- workspace carve-up (all 16B aligned) ----
    float* ws = (float*)d_ws;
    float* x_api  = ws;  ws += (size_t)n_api * NINP;
    float* x_file = ws;  ws += (size_t)n_file * NINP;
    float* agg    = ws;  ws += (size_t)n_file * NH * NINP;
    float* el     = ws;  ws += ((size_t)n_api * NH + 3) & ~3ull;
    float* er     = ws;  ws += ((size_t)n_file * NH + 3) & ~3ull;
    float* Wl     = ws;  ws += NINP * NH + 1;   // 1537 -> keep alignment loose, scalar use only
    float* Wr     = ws;  ws += NINP * NH + 1;
    float* Wcomb  = ws;  ws += (size_t)NH * NINP * NOUT;
    float* bias2  = ws;  ws += NOUT;
    int* cnt    = (int*)ws;
    int* rowptr = cnt + n_file;
    int* cursor = rowptr + n_file + 1;
    int* eidx   = cursor + n_file;

    float* out = (float*)d_out;

    // 1) x_api = emb_api @ Wapi + bapi
    sgemm128<<<dim3(NINP / 128, (n_api + 127) / 128), 256, 0, stream>>>(
        emb_api, NINP, Wapi, NINP, bapi, x_api, NINP, n_api, NINP);
    // 2) x_file = emb_file @ Wfile + bfile
    sgemm128<<<dim3(NINP / 128, (n_file + 127) / 128), 256, 0, stream>>>(
        emb_file, NINP, Wfile, NINP, bfile, x_file, NINP, n_file, NINP);

    // 3) Wl/Wr, bias2
    make_wlr<<<dim3((2 * NINP * NH + 255) / 256), 256, 0, stream>>>(
        Wsrc, Wdst, attn_l, attn_r, Wl, Wr);
    make_bias2<<<1, 256, 0, stream>>>(gat_bias, Whead, bhead, bias2);

    // 4) Wcomb[h] = Wsrc_h (512x256) @ Whead_h (256x256)
    for (int h = 0; h < NH; h++) {
        sgemm128<<<dim3(NOUT / 128, NINP / 128), 256, 0, stream>>>(
            Wsrc + h * NOUT, HD,
            Whead + (size_t)h * NOUT * NOUT, NOUT,
            nullptr,
            Wcomb + (size_t)h * NINP * NOUT, NOUT,
            NINP, NOUT);
    }

    // 5) el = x_api @ Wl, er = x_file @ Wr
    node_attn<<<dim3((n_api + 3) / 4), 256, 0, stream>>>(x_api, Wl, el, n_api);
    node_attn<<<dim3((n_file + 3) / 4), 256, 0, stream>>>(x_file, Wr, er, n_file);

    // 6) CSR over dst
    hipMemsetAsync(cnt, 0, sizeof(int) * n_file, stream);
    count_deg<<<dim3((E + 255) / 256), 256, 0, stream>>>(dst, cnt, E);
    scan_deg<<<1, 1024, 0, stream>>>(cnt, rowptr, cursor, n_file);
    fill_csr<<<dim3((E + 255) / 256), 256, 0, stream>>>(dst, cursor, eidx, E);

    // 7) edge softmax + aggregation
    gat_agg<<<dim3(n_file), 256, 0, stream>>>(rowptr, eidx, src, el, er, x_api, agg);

    // 8) z = agg[20000,1536] @ Wcomb[1536,256] + bias2
    sgemm128<<<dim3(NOUT / 128, (n_file + 127) / 128), 256, 0, stream>>>(
        agg, NH * NINP, Wcomb, NOUT, bias2, out, NOUT, n_file, NH * NINP);
}

// Round 2
// 790.854 us; speedup vs baseline: 1.5911x; 1.5911x over previous
//
#include <hip/hip_runtime.h>
#include <hip/hip_bf16.h>
#include <math.h>

// Problem constants (fixed by the reference)
#define NINP 512
#define NOUT 256
#define NH   3
#define HD   768   // NH*NOUT

typedef short bf8 __attribute__((ext_vector_type(8)));   // 8 bf16 in 4 VGPRs
typedef float f32x4 __attribute__((ext_vector_type(4)));

// ---- bf16 split helpers (manual RN-even, no NaN inputs here) ----
__device__ __forceinline__ unsigned short f2bf(float f) {
    unsigned int u = __float_as_uint(f);
    unsigned int r = (u + 0x7fffu + ((u >> 16) & 1u)) >> 16;
    return (unsigned short)r;
}
__device__ __forceinline__ float bf2f(unsigned short u) {
    return __uint_as_float(((unsigned int)u) << 16);
}

// async global->LDS, 16B per lane
__device__ __forceinline__ void gload16(const void* g, void* l) {
    __builtin_amdgcn_global_load_lds(
        (const void __attribute__((address_space(1)))*)g,
        (void __attribute__((address_space(3)))*)l, 16, 0, 0);
}

// ---------------------------------------------------------------------------
// Elementwise fp32 -> (bf16 hi, bf16 lo).  n4 = n/4.
// ---------------------------------------------------------------------------
__global__ __launch_bounds__(256)
void split_bf16(const float* __restrict__ in, unsigned short* __restrict__ hi,
                unsigned short* __restrict__ lo, size_t n4)
{
    size_t stride = (size_t)gridDim.x * 256;
    for (size_t i = (size_t)blockIdx.x * 256 + threadIdx.x; i < n4; i += stride) {
        float4 v = ((const float4*)in)[i];
        unsigned short h[4], l[4];
#pragma unroll
        for (int j = 0; j < 4; j++) {
            float f = (&v.x)[j];
            h[j] = f2bf(f);
            l[j] = f2bf(f - bf2f(h[j]));
        }
        ((ushort4*)hi)[i] = make_ushort4(h[0], h[1], h[2], h[3]);
        ((ushort4*)lo)[i] = make_ushort4(l[0], l[1], l[2], l[3]);
    }
}

// ---------------------------------------------------------------------------
// in [K][N] fp32  ->  hi/lo [N][K] bf16 (transpose + split). K,N multiples of 32.
// ---------------------------------------------------------------------------
__global__ __launch_bounds__(256)
void transpose_split(const float* __restrict__ in, unsigned short* __restrict__ hi,
                     unsigned short* __restrict__ lo, int K, int N)
{
    __shared__ float t[32][33];
    int x = threadIdx.x & 31;
    int y = threadIdx.x >> 5;   // 0..7
    int k0 = blockIdx.y * 32, n0 = blockIdx.x * 32;
#pragma unroll
    for (int j = 0; j < 4; j++)
        t[y * 4 + j][x] = in[(size_t)(k0 + y * 4 + j) * N + n0 + x];
    __syncthreads();
#pragma unroll
    for (int j = 0; j < 4; j++) {
        float v = t[x][y * 4 + j];
        size_t o = (size_t)(n0 + y * 4 + j) * K + k0 + x;
        unsigned short h = f2bf(v);
        hi[o] = h;
        lo[o] = f2bf(v - bf2f(h));
    }
}

// ---------------------------------------------------------------------------
// WcombT[c][h*512+k] = sum_d Wsrc[k, h*256+d] * Whead[h*256+d, c]  (split bf16)
// grid (512, 3), 256 threads (c).
// ---------------------------------------------------------------------------
__global__ __launch_bounds__(256)
void make_wcomb_t(const float* __restrict__ Wsrc, const float* __restrict__ Whead,
                  unsigned short* __restrict__ hi, unsigned short* __restrict__ lo)
{
    int c = threadIdx.x;
    int k = blockIdx.x;
    int h = blockIdx.y;
    const float* wa = Wsrc + (size_t)k * HD + h * NOUT;
    const float* wb = Whead + (size_t)h * NOUT * NOUT + c;
    float s = 0.f;
    for (int d = 0; d < NOUT; d++)
        s = fmaf(wa[d], wb[(size_t)d * NOUT], s);
    size_t o = (size_t)c * (NH * NINP) + (size_t)h * NINP + k;
    unsigned short hv = f2bf(s);
    hi[o] = hv;
    lo[o] = f2bf(s - bf2f(hv));
}

// ---------------------------------------------------------------------------
// Split-bf16 MFMA GEMM: C[M,N] = (Ah+Al)[M,K] @ (Bh+Bl)^T[N,K]^T + bias.
// B passed TRANSPOSED: Bt[N][K].  N multiple of 128, K multiple of 32 (template).
// 128x128 tile, 4 waves, each 64x64 via 4x4 frags of mfma_f32_16x16x32_bf16.
// 3 MFMAs per frag: hh + hl + lh (ll dropped, ~2^-17 rel err == fp32-class).
// LDS tiles [128 rows][32 k] bf16 with 16B-chunk XOR swizzle (c ^= row&3),
// realized by pre-swizzling the global source address for global_load_lds.
// ---------------------------------------------------------------------------
template<int K>
__global__ __launch_bounds__(256)
void hgemm_split(const unsigned short* __restrict__ Ah, const unsigned short* __restrict__ Al,
                 const unsigned short* __restrict__ Bh, const unsigned short* __restrict__ Bl,
                 const float* __restrict__ bias, float* __restrict__ C, int M, int N)
{
    __shared__ __align__(16) unsigned short sA[2][4096];   // [hi/lo][128*32]
    __shared__ __align__(16) unsigned short sB[2][4096];

    const int tid  = threadIdx.x;
    const int lane = tid & 63;
    const int w    = tid >> 6;        // wave 0..3
    const int wr   = w >> 1, wc = w & 1;
    const int row0 = blockIdx.y * 128;
    const int col0 = blockIdx.x * 128;

    // staging: wave w covers 16B-chunks i = w*128 + q*64 + lane (q=0,1)
    int i0 = w * 128 + lane;
    int r0s = i0 >> 2, c0s = i0 & 3;
    int i1 = i0 + 64;
    int r1s = i1 >> 2, c1s = i1 & 3;
    int ar0 = row0 + r0s; if (ar0 >= M) ar0 = M - 1;
    int ar1 = row0 + r1s; if (ar1 >= M) ar1 = M - 1;
    const size_t offA0 = (size_t)ar0 * K + (size_t)((c0s ^ (r0s & 3)) * 8);
    const size_t offA1 = (size_t)ar1 * K + (size_t)((c1s ^ (r1s & 3)) * 8);
    const size_t offB0 = (size_t)(col0 + r0s) * K + (size_t)((c0s ^ (r0s & 3)) * 8);
    const size_t offB1 = (size_t)(col0 + r1s) * K + (size_t)((c1s ^ (r1s & 3)) * 8);
    unsigned short* lAh0 = &sA[0][0] + w * 1024;
    unsigned short* lAh1 = lAh0 + 512;
    unsigned short* lAl0 = &sA[1][0] + w * 1024;
    unsigned short* lAl1 = lAl0 + 512;
    unsigned short* lBh0 = &sB[0][0] + w * 1024;
    unsigned short* lBh1 = lBh0 + 512;
    unsigned short* lBl0 = &sB[1][0] + w * 1024;
    unsigned short* lBl1 = lBl0 + 512;

    // fragment ds_read offsets: row-swizzled chunk = fg ^ (row&3)
    const int fg = lane >> 4, fr = lane & 15;
    int aoff[4], boff[4];
#pragma unroll
    for (int mi = 0; mi < 4; mi++) {
        int r = wr * 64 + mi * 16 + fr;
        aoff[mi] = r * 32 + ((fg ^ (r & 3)) * 8);
    }
#pragma unroll
    for (int ni = 0; ni < 4; ni++) {
        int r = wc * 64 + ni * 16 + fr;
        boff[ni] = r * 32 + ((fg ^ (r & 3)) * 8);
    }

    f32x4 acc[4][4];
#pragma unroll
    for (int mi = 0; mi < 4; mi++)
#pragma unroll
        for (int ni = 0; ni < 4; ni++)
            acc[mi][ni] = (f32x4){0.f, 0.f, 0.f, 0.f};

    for (int kt = 0; kt < K / 32; kt++) {
        const int kof = kt * 32;
        gload16(Ah + offA0 + kof, lAh0);
        gload16(Ah + offA1 + kof, lAh1);
        gload16(Al + offA0 + kof, lAl0);
        gload16(Al + offA1 + kof, lAl1);
        gload16(Bh + offB0 + kof, lBh0);
        gload16(Bh + offB1 + kof, lBh1);
        gload16(Bl + offB0 + kof, lBl0);
        gload16(Bl + offB1 + kof, lBl1);
        __syncthreads();   // drains vmcnt before barrier (compiler-inserted)

        bf8 a[4][2], b[4][2];
#pragma unroll
        for (int mi = 0; mi < 4; mi++) {
            a[mi][0] = *(const bf8*)&sA[0][aoff[mi]];
            a[mi][1] = *(const bf8*)&sA[1][aoff[mi]];
        }
#pragma unroll
        for (int ni = 0; ni < 4; ni++) {
            b[ni][0] = *(const bf8*)&sB[0][boff[ni]];
            b[ni][1] = *(const bf8*)&sB[1][boff[ni]];
        }
        // pass 1: hi*hi
#pragma unroll
        for (int mi = 0; mi < 4; mi++)
#pragma unroll
            for (int ni = 0; ni < 4; ni++)
                acc[mi][ni] = __builtin_amdgcn_mfma_f32_16x16x32_bf16(a[mi][0], b[ni][0], acc[mi][ni], 0, 0, 0);
        // pass 2: hi*lo
#pragma unroll
        for (int mi = 0; mi < 4; mi++)
#pragma unroll
            for (int ni = 0; ni < 4; ni++)
                acc[mi][ni] = __builtin_amdgcn_mfma_f32_16x16x32_bf16(a[mi][0], b[ni][1], acc[mi][ni], 0, 0, 0);
        // pass 3: lo*hi
#pragma unroll
        for (int mi = 0; mi < 4; mi++)
#pragma unroll
            for (int ni = 0; ni < 4; ni++)
                acc[mi][ni] = __builtin_amdgcn_mfma_f32_16x16x32_bf16(a[mi][1], b[ni][0], acc[mi][ni], 0, 0, 0);
        __syncthreads();
    }

    // epilogue: C/D layout col=lane&15, row=(lane>>4)*4+reg  [verified m89]
#pragma unroll
    for (int ni = 0; ni < 4; ni++) {
        int col = col0 + wc * 64 + ni * 16 + fr;
        float bv = bias ? bias[col] : 0.f;
#pragma unroll
        for (int mi = 0; mi < 4; mi++) {
            int rb = row0 + wr * 64 + mi * 16 + fg * 4;
#pragma unroll
            for (int j = 0; j < 4; j++) {
                int r = rb + j;
                if (r < M) C[(size_t)r * N + col] = acc[mi][ni][j] + bv;
            }
        }
    }
}

// ---------------------------------------------------------------------------
// Wl[k,h] = sum_d Wsrc[k, h*256+d] * attn_l[h,d]   (same for Wr/Wdst/attn_r)
// ---------------------------------------------------------------------------
__global__ void make_wlr(const float* __restrict__ Wsrc, const float* __restrict__ Wdst,
                         const float* __restrict__ attn_l, const float* __restrict__ attn_r,
                         float* __restrict__ Wl, float* __restrict__ Wr)
{
    int t = blockIdx.x * blockDim.x + threadIdx.x;
    if (t >= 2 * NINP * NH) return;
    int which = (t >= NINP * NH) ? 1 : 0;
    int i = t - which * NINP * NH;
    int k = i / NH, h = i % NH;
    const float* W  = which ? Wdst  : Wsrc;
    const float* av = which ? attn_r : attn_l;
    float s = 0.0f;
    for (int d = 0; d < NOUT; d++)
        s = fmaf(W[(size_t)k * HD + h * NOUT + d], av[h * NOUT + d], s);
    (which ? Wr : Wl)[k * NH + h] = s;
}

// bias2[j] = bhead[j] + sum_i gat_bias[i] * Whead[i,j]
__global__ void make_bias2(const float* __restrict__ gat_bias,
                           const float* __restrict__ Whead,
                           const float* __restrict__ bhead,
                           float* __restrict__ bias2)
{
    int j = threadIdx.x;   // 256 threads
    float s = bhead[j];
    for (int i = 0; i < HD; i++)
        s = fmaf(gat_bias[i], Whead[(size_t)i * NOUT + j], s);
    bias2[j] = s;
}

// ---------------------------------------------------------------------------
// el/er: out[n,h] = sum_k x[n,k] * Wv[k,h].   One wave per node.
// ---------------------------------------------------------------------------
__global__ __launch_bounds__(256)
void node_attn(const float* __restrict__ x, const float* __restrict__ Wv,
               float* __restrict__ out, int M)
{
    int node = blockIdx.x * 4 + (threadIdx.x >> 6);
    int lane = threadIdx.x & 63;
    if (node >= M) return;
    const float* xr = x + (size_t)node * NINP;
    float s0 = 0.f, s1 = 0.f, s2 = 0.f;
#pragma unroll
    for (int half = 0; half < 2; half++) {
        int k = half * 256 + lane * 4;
        float4 v = *(const float4*)(xr + k);
#pragma unroll
        for (int j = 0; j < 4; j++) {
            float xv = (&v.x)[j];
            const float* wv = Wv + (size_t)(k + j) * NH;
            s0 = fmaf(xv, wv[0], s0);
            s1 = fmaf(xv, wv[1], s1);
            s2 = fmaf(xv, wv[2], s2);
        }
    }
    for (int o = 32; o > 0; o >>= 1) {
        s0 += __shfl_xor(s0, o);
        s1 += __shfl_xor(s1, o);
        s2 += __shfl_xor(s2, o);
    }
    if (lane == 0) {
        out[node * NH + 0] = s0;
        out[node * NH + 1] = s1;
        out[node * NH + 2] = s2;
    }
}

// ---------------------------------------------------------------------------
// CSR build
// ---------------------------------------------------------------------------
__global__ void count_deg(const int* __restrict__ dst, int* __restrict__ cnt, int E)
{
    int t = blockIdx.x * blockDim.x + threadIdx.x;
    if (t < E) atomicAdd(&cnt[dst[t]], 1);
}

__global__ __launch_bounds__(1024)
void scan_deg(const int* __restrict__ cnt, int* __restrict__ rowptr,
              int* __restrict__ cursor, int n)
{
    __shared__ int tmp[1024];
    __shared__ int s_carry;
    int tid = threadIdx.x;
    if (tid == 0) { rowptr[0] = 0; s_carry = 0; }
    __syncthreads();
    for (int base = 0; base < n; base += 1024) {
        int i = base + tid;
        int v = (i < n) ? cnt[i] : 0;
        tmp[tid] = v;
        __syncthreads();
        for (int off = 1; off < 1024; off <<= 1) {
            int add = (tid >= off) ? tmp[tid - off] : 0;
            __syncthreads();
            tmp[tid] += add;
            __syncthreads();
        }
        int carry = s_carry;
        if (i < n) {
            int incl = carry + tmp[tid];
            rowptr[i + 1] = incl;
            cursor[i] = incl - v;     // exclusive prefix = segment start
        }
        __syncthreads();
        if (tid == 1023) s_carry = carry + tmp[1023];
        __syncthreads();
    }
}

__global__ void fill_csr(const int* __restrict__ dst, int* __restrict__ cursor,
                         int* __restrict__ eidx, int E)
{
    int t = blockIdx.x * blockDim.x + threadIdx.x;
    if (t < E) {
        int p = atomicAdd(&cursor[dst[t]], 1);
        eidx[p] = t;
    }
}

// ---------------------------------------------------------------------------
// Per-dst-node edge softmax + aggregation; emits agg as split bf16 hi/lo:
//   agg[n,h,k] = sum_{e: dst=n} alpha[e,h] * x_api[src[e], k]
// One block (256 threads) per dst node; thread owns 2 k-cols x 3 heads.
// ---------------------------------------------------------------------------
__device__ __forceinline__ void store2(unsigned short* hi, unsigned short* lo,
                                       size_t off, float v0, float v1)
{
    unsigned short h0 = f2bf(v0), h1 = f2bf(v1);
    unsigned short l0 = f2bf(v0 - bf2f(h0)), l1 = f2bf(v1 - bf2f(h1));
    *(unsigned int*)(hi + off) = (unsigned int)h0 | ((unsigned int)h1 << 16);
    *(unsigned int*)(lo + off) = (unsigned int)l0 | ((unsigned int)l1 << 16);
}

#define MAXC 256
__global__ __launch_bounds__(256)
void gat_agg(const int* __restrict__ rowptr, const int* __restrict__ eidx,
             const int* __restrict__ src,
             const float* __restrict__ el, const float* __restrict__ er,
             const float* __restrict__ x,
             unsigned short* __restrict__ aggH, unsigned short* __restrict__ aggL)
{
    int n = blockIdx.x;
    int t = threadIdx.x;
    int beg = rowptr[n], end = rowptr[n + 1];
    int deg = end - beg;

    __shared__ float s_red[4][3];
    __shared__ float s_alpha[MAXC][3];
    __shared__ int   s_src[MAXC];

    float a00 = 0.f, a01 = 0.f, a10 = 0.f, a11 = 0.f, a20 = 0.f, a21 = 0.f;

    if (deg > 0) {
        const float er0 = er[n * NH + 0], er1 = er[n * NH + 1], er2 = er[n * NH + 2];

        // ---- pass 1: per-head max ----
        float m0 = -1e30f, m1 = -1e30f, m2 = -1e30f;
        for (int i = t; i < deg; i += 256) {
            int e = eidx[beg + i]; int s = src[e];
            float v0 = el[s * NH + 0] + er0; v0 = v0 > 0.f ? v0 : 0.2f * v0;
            float v1 = el[s * NH + 1] + er1; v1 = v1 > 0.f ? v1 : 0.2f * v1;
            float v2 = el[s * NH + 2] + er2; v2 = v2 > 0.f ? v2 : 0.2f * v2;
            m0 = fmaxf(m0, v0); m1 = fmaxf(m1, v1); m2 = fmaxf(m2, v2);
        }
        for (int o = 32; o > 0; o >>= 1) {
            m0 = fmaxf(m0, __shfl_xor(m0, o));
            m1 = fmaxf(m1, __shfl_xor(m1, o));
            m2 = fmaxf(m2, __shfl_xor(m2, o));
        }
        if ((t & 63) == 0) { int wv = t >> 6; s_red[wv][0] = m0; s_red[wv][1] = m1; s_red[wv][2] = m2; }
        __syncthreads();
        m0 = fmaxf(fmaxf(s_red[0][0], s_red[1][0]), fmaxf(s_red[2][0], s_red[3][0]));
        m1 = fmaxf(fmaxf(s_red[0][1], s_red[1][1]), fmaxf(s_red[2][1], s_red[3][1]));
        m2 = fmaxf(fmaxf(s_red[0][2], s_red[1][2]), fmaxf(s_red[2][2], s_red[3][2]));
        __syncthreads();

        // ---- pass 2: per-head sum of exp ----
        float z0 = 0.f, z1 = 0.f, z2 = 0.f;
        for (int i = t; i < deg; i += 256) {
            int e = eidx[beg + i]; int s = src[e];
            float v0 = el[s * NH + 0] + er0; v0 = v0 > 0.f ? v0 : 0.2f * v0;
            float v1 = el[s * NH + 1] + er1; v1 = v1 > 0.f ? v1 : 0.2f * v1;
            float v2 = el[s * NH + 2] + er2; v2 = v2 > 0.f ? v2 : 0.2f * v2;
            z0 += expf(v0 - m0); z1 += expf(v1 - m1); z2 += expf(v2 - m2);
        }
        for (int o = 32; o > 0; o >>= 1) {
            z0 += __shfl_xor(z0, o); z1 += __shfl_xor(z1, o); z2 += __shfl_xor(z2, o);
        }
        if ((t & 63) == 0) { int wv = t >> 6; s_red[wv][0] = z0; s_red[wv][1] = z1; s_red[wv][2] = z2; }
        __syncthreads();
        z0 = s_red[0][0] + s_red[1][0] + s_red[2][0] + s_red[3][0];
        z1 = s_red[0][1] + s_red[1][1] + s_red[2][1] + s_red[3][1];
        z2 = s_red[0][2] + s_red[1][2] + s_red[2][2] + s_red[3][2];
        __syncthreads();
        const float inv0 = 1.0f / z0, inv1 = 1.0f / z1, inv2 = 1.0f / z2;

        // ---- pass 3: alpha + aggregate, in chunks of MAXC edges ----
        for (int base = 0; base < deg; base += MAXC) {
            int cn = min(MAXC, deg - base);
            for (int i = t; i < cn; i += 256) {
                int e = eidx[beg + base + i]; int s = src[e];
                float v0 = el[s * NH + 0] + er0; v0 = v0 > 0.f ? v0 : 0.2f * v0;
                float v1 = el[s * NH + 1] + er1; v1 = v1 > 0.f ? v1 : 0.2f * v1;
                float v2 = el[s * NH + 2] + er2; v2 = v2 > 0.f ? v2 : 0.2f * v2;
                s_alpha[i][0] = expf(v0 - m0) * inv0;
                s_alpha[i][1] = expf(v1 - m1) * inv1;
                s_alpha[i][2] = expf(v2 - m2) * inv2;
                s_src[i] = s;
            }
            __syncthreads();
            for (int i = 0; i < cn; i++) {
                int s = s_src[i];
                float c0 = s_alpha[i][0], c1 = s_alpha[i][1], c2 = s_alpha[i][2];
                float2 xv = *(const float2*)(x + (size_t)s * NINP + 2 * t);
                a00 = fmaf(c0, xv.x, a00); a01 = fmaf(c0, xv.y, a01);
                a10 = fmaf(c1, xv.x, a10); a11 = fmaf(c1, xv.y, a11);
                a20 = fmaf(c2, xv.x, a20); a21 = fmaf(c2, xv.y, a21);
            }
            __syncthreads();
        }
    }

    size_t b = (size_t)n * (NH * NINP) + 2 * t;
    store2(aggH, aggL, b,             a00, a01);
    store2(aggH, aggL, b + NINP,      a10, a11);
    store2(aggH, aggL, b + 2 * NINP,  a20, a21);
}

// ---------------------------------------------------------------------------
extern "C" void kernel_launch(void* const* d_in, const int* in_sizes, int n_in,
                              void* d_out, int out_size, void* d_ws, size_t ws_size,
                              hipStream_t stream)
{
    const float* emb_api  = (const float*)d_in[0];
    const float* emb_file = (const float*)d_in[1];
    // d_in[2] (e_tensor) unused by the reference
    const int*   src      = (const int*)d_in[3];
    const int*   dst      = (const int*)d_in[4];
    const float* Wapi     = (const float*)d_in[5];
    const float* bapi     = (const float*)d_in[6];
    const float* Wfile    = (const float*)d_in[7];
    const float* bfile    = (const float*)d_in[8];
    const float* Wsrc     = (const float*)d_in[9];
    const float* Wdst     = (const float*)d_in[10];
    const float* attn_l   = (const float*)d_in[11];
    const float* attn_r   = (const float*)d_in[12];
    const float* gat_bias = (const float*)d_in[13];
    const float* Whead    = (const float*)d_in[14];
    const float* bhead    = (const float*)d_in[15];

    const int n_api  = in_sizes[0] / NINP;   // 50000
    const int n_file = in_sizes[1] / NINP;   // 20000
    const int E      = in_sizes[2];          // 250000

    // ---- workspace carve-up ----
    char* p = (char*)d_ws;
    auto alloc = [&](size_t bytes) -> void* {
        void* r = (void*)p;
        p += (bytes + 255) & ~(size_t)255;
        return r;
    };

    float* x_api  = (float*)alloc((size_t)n_api * NINP * 4);
    float* x_file = (float*)alloc((size_t)n_file * NINP * 4);

    // union region: {Ahi,Alo,Fhi,Flo} then reused as {aggH,aggL}
    size_t szA = (size_t)n_api  * NINP * 2;
    size_t szF = (size_t)n_file * NINP * 2;
    size_t szG = (size_t)n_file * NH * NINP * 2;
    size_t usz = 2 * szA + 2 * szF; if (2 * szG > usz) usz = 2 * szG;
    char* U = (char*)alloc(usz);
    unsigned short* Ahi  = (unsigned short*)U;
    unsigned short* Alo  = (unsigned short*)(U + szA);
    unsigned short* Fhi  = (unsigned short*)(U + 2 * szA);
    unsigned short* Flo  = (unsigned short*)(U + 2 * szA + szF);
    unsigned short* aggH = (unsigned short*)U;            // alias (disjoint lifetime)
    unsigned short* aggL = (unsigned short*)(U + szG);

    unsigned short* WapiTh  = (unsigned short*)alloc((size_t)NINP * NINP * 2);
    unsigned short* WapiTl  = (unsigned short*)alloc((size_t)NINP * NINP * 2);
    unsigned short* WfileTh = (unsigned short*)alloc((size_t)NINP * NINP * 2);
    unsigned short* WfileTl = (unsigned short*)alloc((size_t)NINP * NINP * 2);
    unsigned short* WctH    = (unsigned short*)alloc((size_t)NOUT * NH * NINP * 2);
    unsigned short* WctL    = (unsigned short*)alloc((size_t)NOUT * NH * NINP * 2);
    float* el    = (float*)alloc((size_t)n_api  * NH * 4);
    float* er    = (float*)alloc((size_t)n_file * NH * 4);
    float* Wl    = (float*)alloc((size_t)NINP * NH * 4);
    float* Wr    = (float*)alloc((size_t)NINP * NH * 4);
    float* bias2 = (float*)alloc((size_t)NOUT * 4);
    int* cnt    = (int*)alloc((size_t)n_file * 4);
    int* rowptr = (int*)alloc((size_t)(n_file + 1) * 4);
    int* cursor = (int*)alloc((size_t)n_file * 4);
    int* eidx   = (int*)alloc((size_t)E * 4);

    float* out = (float*)d_out;

    // 1) split inputs to bf16 hi/lo
    split_bf16<<<dim3(2048), 256, 0, stream>>>(emb_api,  Ahi, Alo, (size_t)n_api  * NINP / 4);
    split_bf16<<<dim3(1024), 256, 0, stream>>>(emb_file, Fhi, Flo, (size_t)n_file * NINP / 4);
    transpose_split<<<dim3(NINP / 32, NINP / 32), 256, 0, stream>>>(Wapi,  WapiTh,  WapiTl,  NINP, NINP);
    transpose_split<<<dim3(NINP / 32, NINP / 32), 256, 0, stream>>>(Wfile, WfileTh, WfileTl, NINP, NINP);

    // 2) small weight prep
    make_wlr<<<dim3((2 * NINP * NH + 255) / 256), 256, 0, stream>>>(Wsrc, Wdst, attn_l, attn_r, Wl, Wr);
    make_bias2<<<1, 256, 0, stream>>>(gat_bias, Whead, bhead, bias2);
    make_wcomb_t<<<dim3(NINP, NH), 256, 0, stream>>>(Wsrc, Whead, WctH, WctL);

    // 3) projections via split-bf16 MFMA
    hgemm_split<NINP><<<dim3(NINP / 128, (n_api + 127) / 128), 256, 0, stream>>>(
        Ahi, Alo, WapiTh, WapiTl, bapi, x_api, n_api, NINP);
    hgemm_split<NINP><<<dim3(NINP / 128, (n_file + 127) / 128), 256, 0, stream>>>(
        Fhi, Flo, WfileTh, WfileTl, bfile, x_file, n_file, NINP);

    // 4) el / er
    node_attn<<<dim3((n_api + 3) / 4), 256, 0, stream>>>(x_api, Wl, el, n_api);
    node_attn<<<dim3((n_file + 3) / 4), 256, 0, stream>>>(x_file, Wr, er, n_file);

    // 5) CSR over dst
    hipMemsetAsync(cnt, 0, sizeof(int) * n_file, stream);
    count_deg<<<dim3((E + 255) / 256), 256, 0, stream>>>(dst, cnt, E);
    scan_deg<<<1, 1024, 0, stream>>>(cnt, rowptr, cursor, n_file);
    fill_csr<<<dim3((E + 255) / 256), 256, 0, stream>>>(dst, cursor, eidx, E);

    // 6) edge softmax + aggregation (emits split-bf16 agg)
    gat_agg<<<dim3(n_file), 256, 0, stream>>>(rowptr, eidx, src, el, er, x_api, aggH, aggL);

    // 7) z = agg[20000,1536] @ Wcomb[1536,256] + bias2, via split-bf16 MFMA
    hgemm_split<NH * NINP><<<dim3(NOUT / 128, (n_file + 127) / 128), 256, 0, stream>>>(
        aggH, aggL, WctH, WctL, bias2, out, n_file, NOUT);
}

// Round 3
// 689.962 us; speedup vs baseline: 1.8238x; 1.1462x over previous
//
#include <hip/hip_runtime.h>
#include <hip/hip_bf16.h>
#include <math.h>

// Problem constants (fixed by the reference)
#define NINP 512
#define NOUT 256
#define NH   3
#define HD   768   // NH*NOUT

typedef short bf8 __attribute__((ext_vector_type(8)));     // 8 bf16 in 4 VGPRs
typedef short short8v __attribute__((ext_vector_type(8)));
typedef float f32x4 __attribute__((ext_vector_type(4)));

// ---- bf16 split helpers (manual RN-even) ----
__device__ __forceinline__ unsigned short f2bf(float f) {
    unsigned int u = __float_as_uint(f);
    unsigned int r = (u + 0x7fffu + ((u >> 16) & 1u)) >> 16;
    return (unsigned short)r;
}
__device__ __forceinline__ float bf2f(unsigned short u) {
    return __uint_as_float(((unsigned int)u) << 16);
}

// async global->LDS, 16B per lane
__device__ __forceinline__ void gload16(const void* g, void* l) {
    __builtin_amdgcn_global_load_lds(
        (const void __attribute__((address_space(1)))*)g,
        (void __attribute__((address_space(3)))*)l, 16, 0, 0);
}

// ---------------------------------------------------------------------------
// make_attn_w: 6 blocks (side l/r x head h).
//   Wl[j]   = sum_d Wgat[j, h*256+d] * attn[h,d]            (LDS)
//   W2[k,h] = sum_j Wproj[k,j] * Wl[j]                      (global, [512][3])
//   cvec[h] = sum_j bproj[j] * Wl[j]
// ---------------------------------------------------------------------------
__global__ __launch_bounds__(256)
void make_attn_w(const float* __restrict__ Wsrc, const float* __restrict__ Wdst,
                 const float* __restrict__ attn_l, const float* __restrict__ attn_r,
                 const float* __restrict__ Wapi, const float* __restrict__ Wfile,
                 const float* __restrict__ bapi, const float* __restrict__ bfile,
                 float* __restrict__ Wl2, float* __restrict__ Wr2,
                 float* __restrict__ elc, float* __restrict__ erc)
{
    __shared__ float wl[NINP];
    __shared__ float red[256];
    int b = blockIdx.x;
    int side = (b >= NH) ? 1 : 0;
    int h = b - side * NH;
    const float* Wg = side ? Wdst : Wsrc;
    const float* av = side ? attn_r : attn_l;
    const float* Wp = side ? Wfile : Wapi;
    const float* bp = side ? bfile : bapi;
    float* W2 = side ? Wr2 : Wl2;
    float* cv = side ? erc : elc;
    int t = threadIdx.x;

#pragma unroll
    for (int rep = 0; rep < 2; rep++) {
        int j = t + rep * 256;
        const float* wr = Wg + (size_t)j * HD + h * NOUT;
        const float* ar = av + h * NOUT;
        float s = 0.f;
        for (int d = 0; d < NOUT; d++) s = fmaf(wr[d], ar[d], s);
        wl[j] = s;
    }
    __syncthreads();

#pragma unroll
    for (int rep = 0; rep < 2; rep++) {
        int k = t + rep * 256;
        const float* pr = Wp + (size_t)k * NINP;
        float s = 0.f;
        for (int j = 0; j < NINP; j++) s = fmaf(pr[j], wl[j], s);
        W2[k * NH + h] = s;
    }
    // bias const
    float sb = fmaf(bp[t], wl[t], bp[t + 256] * wl[t + 256]);
    red[t] = sb;
    __syncthreads();
    for (int o = 128; o > 0; o >>= 1) {
        if (t < o) red[t] += red[t + o];
        __syncthreads();
    }
    if (t == 0) cv[h] = red[0];
}

// ---------------------------------------------------------------------------
// WcombT[c][h*512+k] = sum_d Wsrc[k, h*256+d] * Whead[h*256+d, c]  (split bf16)
// grid (512, 3), 256 threads (c).  Block (0,0) also computes bias2.
// ---------------------------------------------------------------------------
__global__ __launch_bounds__(256)
void make_wcomb_t(const float* __restrict__ Wsrc, const float* __restrict__ Whead,
                  const float* __restrict__ gat_bias, const float* __restrict__ bhead,
                  unsigned short* __restrict__ hi, unsigned short* __restrict__ lo,
                  float* __restrict__ bias2)
{
    int c = threadIdx.x;
    int k = blockIdx.x;
    int h = blockIdx.y;
    const float* wa = Wsrc + (size_t)k * HD + h * NOUT;
    const float* wb = Whead + (size_t)h * NOUT * NOUT + c;
    float s = 0.f;
    for (int d = 0; d < NOUT; d++)
        s = fmaf(wa[d], wb[(size_t)d * NOUT], s);
    size_t o = (size_t)c * (NH * NINP) + (size_t)h * NINP + k;
    unsigned short hv = f2bf(s);
    hi[o] = hv;
    lo[o] = f2bf(s - bf2f(hv));

    if (k == 0 && h == 0) {
        float sb = bhead[c];
        for (int i = 0; i < HD; i++)
            sb = fmaf(gat_bias[i], Whead[(size_t)i * NOUT + c], sb);
        bias2[c] = sb;
    }
}

// ---------------------------------------------------------------------------
// in [K][N] fp32  ->  hi/lo [N][K] bf16 (transpose + split). 32x32 tiles.
// ---------------------------------------------------------------------------
__global__ __launch_bounds__(256)
void transpose_split(const float* __restrict__ in, unsigned short* __restrict__ hi,
                     unsigned short* __restrict__ lo, int K, int N)
{
    __shared__ float t[32][33];
    int x = threadIdx.x & 31;
    int y = threadIdx.x >> 5;   // 0..7
    int k0 = blockIdx.y * 32, n0 = blockIdx.x * 32;
#pragma unroll
    for (int j = 0; j < 4; j++)
        t[y * 4 + j][x] = in[(size_t)(k0 + y * 4 + j) * N + n0 + x];
    __syncthreads();
#pragma unroll
    for (int j = 0; j < 4; j++) {
        float v = t[x][y * 4 + j];
        size_t o = (size_t)(n0 + y * 4 + j) * K + k0 + x;
        unsigned short h = f2bf(v);
        hi[o] = h;
        lo[o] = f2bf(v - bf2f(h));
    }
}

// ---------------------------------------------------------------------------
// split_el<STORE>: one wave per row of emb[M][512].
//   If STORE: write hi/lo bf16 split of the row.
//   Always: el[row,h] = row . W2[:,h] + cvec[h]   (W2 [512][3])
// ---------------------------------------------------------------------------
template<bool STORE>
__global__ __launch_bounds__(256)
void split_el(const float* __restrict__ emb, const float* __restrict__ W2,
              const float* __restrict__ cvec,
              unsigned short* __restrict__ hi, unsigned short* __restrict__ lo,
              float* __restrict__ elout, int M)
{
    const int lane = threadIdx.x & 63;
    const int k0 = lane * 8;
    // preload this lane's 8x3 weight block into registers
    float w[8][3];
#pragma unroll
    for (int j = 0; j < 8; j++) {
#pragma unroll
        for (int h = 0; h < NH; h++)
            w[j][h] = W2[(k0 + j) * NH + h];
    }
    const float c0 = cvec[0], c1 = cvec[1], c2 = cvec[2];

    int wid = blockIdx.x * 4 + (threadIdx.x >> 6);
    int nw = gridDim.x * 4;
    for (int row = wid; row < M; row += nw) {
        const float* r = emb + (size_t)row * NINP + k0;
        float4 v0 = *(const float4*)r;
        float4 v1 = *(const float4*)(r + 4);
        float x[8] = {v0.x, v0.y, v0.z, v0.w, v1.x, v1.y, v1.z, v1.w};
        if (STORE) {
            short8v hv, lv;
#pragma unroll
            for (int j = 0; j < 8; j++) {
                unsigned short hb = f2bf(x[j]);
                hv[j] = (short)hb;
                lv[j] = (short)f2bf(x[j] - bf2f(hb));
            }
            *(short8v*)(hi + (size_t)row * NINP + k0) = hv;
            *(short8v*)(lo + (size_t)row * NINP + k0) = lv;
        }
        float s0 = 0.f, s1 = 0.f, s2 = 0.f;
#pragma unroll
        for (int j = 0; j < 8; j++) {
            s0 = fmaf(x[j], w[j][0], s0);
            s1 = fmaf(x[j], w[j][1], s1);
            s2 = fmaf(x[j], w[j][2], s2);
        }
        for (int o = 32; o > 0; o >>= 1) {
            s0 += __shfl_xor(s0, o);
            s1 += __shfl_xor(s1, o);
            s2 += __shfl_xor(s2, o);
        }
        if (lane == 0) {
            elout[row * NH + 0] = s0 + c0;
            elout[row * NH + 1] = s1 + c1;
            elout[row * NH + 2] = s2 + c2;
        }
    }
}

// ---------------------------------------------------------------------------
// Split-bf16 MFMA GEMM: C = (Ah+Al)[M,K] @ (Bh+Bl)[N,K]^T + bias.
// 128x128 tile, 4 waves, 4x4 frags of mfma_f32_16x16x32_bf16, 3 passes
// (hh+hl+lh).  LDS [128][32] bf16, chunk swizzle c ^= (r>>1)&3 (conflict-free
// within 16-lane phases), realized by pre-swizzled global source addresses.
// Bijective XCD-chunked block swizzle (m204) for L2 panel reuse.
// If PACK: C is uint* with (hi | lo<<16) bf16 split packing.
// ---------------------------------------------------------------------------
template<int K, bool PACK>
__global__ __launch_bounds__(256)
void hgemm_split(const unsigned short* __restrict__ Ah, const unsigned short* __restrict__ Al,
                 const unsigned short* __restrict__ Bh, const unsigned short* __restrict__ Bl,
                 const float* __restrict__ bias, void* __restrict__ Cv, int M, int N)
{
    __shared__ __align__(16) unsigned short sA[2][4096];   // [hi/lo][128*32]
    __shared__ __align__(16) unsigned short sB[2][4096];

    // ---- bijective XCD-chunked remap of the flat block id ----
    const int nwg = gridDim.x * gridDim.y;
    int flat = blockIdx.y * gridDim.x + blockIdx.x;
    {
        const int q = nwg >> 3, rr = nwg & 7;
        int xcd = flat & 7, idx = flat >> 3;
        flat = (xcd < rr) ? (xcd * (q + 1) + idx)
                          : (rr * (q + 1) + (xcd - rr) * q + idx);
    }
    const int row0 = (flat / gridDim.x) * 128;
    const int col0 = (flat % gridDim.x) * 128;

    const int tid  = threadIdx.x;
    const int lane = tid & 63;
    const int w    = tid >> 6;        // wave 0..3
    const int wr   = w >> 1, wc = w & 1;

    // staging: wave w covers 16B-chunks i = w*128 + {0,64} + lane
    int i0 = w * 128 + lane;
    int r0s = i0 >> 2, c0s = i0 & 3;
    int i1 = i0 + 64;
    int r1s = i1 >> 2, c1s = i1 & 3;
    int ar0 = row0 + r0s; if (ar0 >= M) ar0 = M - 1;
    int ar1 = row0 + r1s; if (ar1 >= M) ar1 = M - 1;
    const size_t offA0 = (size_t)ar0 * K + (size_t)((c0s ^ ((r0s >> 1) & 3)) * 8);
    const size_t offA1 = (size_t)ar1 * K + (size_t)((c1s ^ ((r1s >> 1) & 3)) * 8);
    const size_t offB0 = (size_t)(col0 + r0s) * K + (size_t)((c0s ^ ((r0s >> 1) & 3)) * 8);
    const size_t offB1 = (size_t)(col0 + r1s) * K + (size_t)((c1s ^ ((r1s >> 1) & 3)) * 8);
    unsigned short* lAh0 = &sA[0][0] + w * 1024;
    unsigned short* lAh1 = lAh0 + 512;
    unsigned short* lAl0 = &sA[1][0] + w * 1024;
    unsigned short* lAl1 = lAl0 + 512;
    unsigned short* lBh0 = &sB[0][0] + w * 1024;
    unsigned short* lBh1 = lBh0 + 512;
    unsigned short* lBl0 = &sB[1][0] + w * 1024;
    unsigned short* lBl1 = lBl0 + 512;

    // fragment ds_read offsets: chunk = fg ^ ((r>>1)&3)
    const int fg = lane >> 4, fr = lane & 15;
    int aoff[4], boff[4];
#pragma unroll
    for (int mi = 0; mi < 4; mi++) {
        int r = wr * 64 + mi * 16 + fr;
        aoff[mi] = r * 32 + ((fg ^ ((r >> 1) & 3)) * 8);
    }
#pragma unroll
    for (int ni = 0; ni < 4; ni++) {
        int r = wc * 64 + ni * 16 + fr;
        boff[ni] = r * 32 + ((fg ^ ((r >> 1) & 3)) * 8);
    }

    f32x4 acc[4][4];
#pragma unroll
    for (int mi = 0; mi < 4; mi++)
#pragma unroll
        for (int ni = 0; ni < 4; ni++)
            acc[mi][ni] = (f32x4){0.f, 0.f, 0.f, 0.f};

    for (int kt = 0; kt < K / 32; kt++) {
        const int kof = kt * 32;
        gload16(Ah + offA0 + kof, lAh0);
        gload16(Ah + offA1 + kof, lAh1);
        gload16(Al + offA0 + kof, lAl0);
        gload16(Al + offA1 + kof, lAl1);
        gload16(Bh + offB0 + kof, lBh0);
        gload16(Bh + offB1 + kof, lBh1);
        gload16(Bl + offB0 + kof, lBl0);
        gload16(Bl + offB1 + kof, lBl1);
        __syncthreads();

        bf8 a[4][2], b[4][2];
#pragma unroll
        for (int mi = 0; mi < 4; mi++) {
            a[mi][0] = *(const bf8*)&sA[0][aoff[mi]];
            a[mi][1] = *(const bf8*)&sA[1][aoff[mi]];
        }
#pragma unroll
        for (int ni = 0; ni < 4; ni++) {
            b[ni][0] = *(const bf8*)&sB[0][boff[ni]];
            b[ni][1] = *(const bf8*)&sB[1][boff[ni]];
        }
#pragma unroll
        for (int mi = 0; mi < 4; mi++)
#pragma unroll
            for (int ni = 0; ni < 4; ni++)
                acc[mi][ni] = __builtin_amdgcn_mfma_f32_16x16x32_bf16(a[mi][0], b[ni][0], acc[mi][ni], 0, 0, 0);
#pragma unroll
        for (int mi = 0; mi < 4; mi++)
#pragma unroll
            for (int ni = 0; ni < 4; ni++)
                acc[mi][ni] = __builtin_amdgcn_mfma_f32_16x16x32_bf16(a[mi][0], b[ni][1], acc[mi][ni], 0, 0, 0);
#pragma unroll
        for (int mi = 0; mi < 4; mi++)
#pragma unroll
            for (int ni = 0; ni < 4; ni++)
                acc[mi][ni] = __builtin_amdgcn_mfma_f32_16x16x32_bf16(a[mi][1], b[ni][0], acc[mi][ni], 0, 0, 0);
        __syncthreads();
    }

    // epilogue: C/D layout col=lane&15, row=(lane>>4)*4+reg  [verified m89]
#pragma unroll
    for (int ni = 0; ni < 4; ni++) {
        int col = col0 + wc * 64 + ni * 16 + fr;
        float bv = bias ? bias[col] : 0.f;
#pragma unroll
        for (int mi = 0; mi < 4; mi++) {
            int rb = row0 + wr * 64 + mi * 16 + fg * 4;
#pragma unroll
            for (int j = 0; j < 4; j++) {
                int r = rb + j;
                if (r < M) {
                    float v = acc[mi][ni][j] + bv;
                    if (PACK) {
                        unsigned short hb = f2bf(v);
                        unsigned short lb = f2bf(v - bf2f(hb));
                        ((unsigned int*)Cv)[(size_t)r * N + col] =
                            (unsigned int)hb | ((unsigned int)lb << 16);
                    } else {
                        ((float*)Cv)[(size_t)r * N + col] = v;
                    }
                }
            }
        }
    }
}

// ---------------------------------------------------------------------------
// CSR build
// ---------------------------------------------------------------------------
__global__ void count_deg(const int* __restrict__ dst, int* __restrict__ cnt, int E)
{
    int t = blockIdx.x * blockDim.x + threadIdx.x;
    if (t < E) atomicAdd(&cnt[dst[t]], 1);
}

__global__ __launch_bounds__(1024)
void scan_deg(const int* __restrict__ cnt, int* __restrict__ rowptr,
              int* __restrict__ cursor, int n)
{
    __shared__ int wsum[16];
    __shared__ int s_carry;
    int tid = threadIdx.x;
    int lane = tid & 63, wid = tid >> 6;
    if (tid == 0) { rowptr[0] = 0; s_carry = 0; }
    __syncthreads();
    for (int base = 0; base < n; base += 1024) {
        int i = base + tid;
        int v = (i < n) ? cnt[i] : 0;
        int s = v;
#pragma unroll
        for (int o = 1; o < 64; o <<= 1) {
            int u = __shfl_up(s, o);
            if (lane >= o) s += u;
        }
        if (lane == 63) wsum[wid] = s;
        __syncthreads();
        if (wid == 0) {
            int ws = (lane < 16) ? wsum[lane] : 0;
#pragma unroll
            for (int o = 1; o < 16; o <<= 1) {
                int u = __shfl_up(ws, o);
                if (lane >= o) ws += u;
            }
            if (lane < 16) wsum[lane] = ws;
        }
        __syncthreads();
        int carry = s_carry;
        int incl = carry + (wid ? wsum[wid - 1] : 0) + s;
        if (i < n) {
            rowptr[i + 1] = incl;
            cursor[i] = incl - v;
        }
        __syncthreads();
        if (tid == 1023) s_carry = incl;
        __syncthreads();
    }
}

__global__ void fill_csr(const int* __restrict__ dst, int* __restrict__ cursor,
                         int* __restrict__ eidx, int E)
{
    int t = blockIdx.x * blockDim.x + threadIdx.x;
    if (t < E) {
        int p = atomicAdd(&cursor[dst[t]], 1);
        eidx[p] = t;
    }
}

// ---------------------------------------------------------------------------
// Per-dst-node edge softmax + aggregation; x is packed hi|lo<<16 uint/elem;
// emits agg as split bf16 hi/lo.
// ---------------------------------------------------------------------------
__device__ __forceinline__ void store2(unsigned short* hi, unsigned short* lo,
                                       size_t off, float v0, float v1)
{
    unsigned short h0 = f2bf(v0), h1 = f2bf(v1);
    unsigned short l0 = f2bf(v0 - bf2f(h0)), l1 = f2bf(v1 - bf2f(h1));
    *(unsigned int*)(hi + off) = (unsigned int)h0 | ((unsigned int)h1 << 16);
    *(unsigned int*)(lo + off) = (unsigned int)l0 | ((unsigned int)l1 << 16);
}

#define MAXC 256
__global__ __launch_bounds__(256)
void gat_agg(const int* __restrict__ rowptr, const int* __restrict__ eidx,
             const int* __restrict__ src,
             const float* __restrict__ el, const float* __restrict__ er,
             const unsigned int* __restrict__ xHL,
             unsigned short* __restrict__ aggH, unsigned short* __restrict__ aggL)
{
    int n = blockIdx.x;
    int t = threadIdx.x;
    int beg = rowptr[n], end = rowptr[n + 1];
    int deg = end - beg;

    __shared__ float s_red[4][3];
    __shared__ float s_alpha[MAXC][3];
    __shared__ int   s_src[MAXC];

    float a00 = 0.f, a01 = 0.f, a10 = 0.f, a11 = 0.f, a20 = 0.f, a21 = 0.f;

    if (deg > 0) {
        const float er0 = er[n * NH + 0], er1 = er[n * NH + 1], er2 = er[n * NH + 2];

        float m0 = -1e30f, m1 = -1e30f, m2 = -1e30f;
        for (int i = t; i < deg; i += 256) {
            int e = eidx[beg + i]; int s = src[e];
            float v0 = el[s * NH + 0] + er0; v0 = v0 > 0.f ? v0 : 0.2f * v0;
            float v1 = el[s * NH + 1] + er1; v1 = v1 > 0.f ? v1 : 0.2f * v1;
            float v2 = el[s * NH + 2] + er2; v2 = v2 > 0.f ? v2 : 0.2f * v2;
            m0 = fmaxf(m0, v0); m1 = fmaxf(m1, v1); m2 = fmaxf(m2, v2);
        }
        for (int o = 32; o > 0; o >>= 1) {
            m0 = fmaxf(m0, __shfl_xor(m0, o));
            m1 = fmaxf(m1, __shfl_xor(m1, o));
            m2 = fmaxf(m2, __shfl_xor(m2, o));
        }
        if ((t & 63) == 0) { int wv = t >> 6; s_red[wv][0] = m0; s_red[wv][1] = m1; s_red[wv][2] = m2; }
        __syncthreads();
        m0 = fmaxf(fmaxf(s_red[0][0], s_red[1][0]), fmaxf(s_red[2][0], s_red[3][0]));
        m1 = fmaxf(fmaxf(s_red[0][1], s_red[1][1]), fmaxf(s_red[2][1], s_red[3][1]));
        m2 = fmaxf(fmaxf(s_red[0][2], s_red[1][2]), fmaxf(s_red[2][2], s_red[3][2]));
        __syncthreads();

        float z0 = 0.f, z1 = 0.f, z2 = 0.f;
        for (int i = t; i < deg; i += 256) {
            int e = eidx[beg + i]; int s = src[e];
            float v0 = el[s * NH + 0] + er0; v0 = v0 > 0.f ? v0 : 0.2f * v0;
            float v1 = el[s * NH + 1] + er1; v1 = v1 > 0.f ? v1 : 0.2f * v1;
            float v2 = el[s * NH + 2] + er2; v2 = v2 > 0.f ? v2 : 0.2f * v2;
            z0 += expf(v0 - m0); z1 += expf(v1 - m1); z2 += expf(v2 - m2);
        }
        for (int o = 32; o > 0; o >>= 1) {
            z0 += __shfl_xor(z0, o); z1 += __shfl_xor(z1, o); z2 += __shfl_xor(z2, o);
        }
        if ((t & 63) == 0) { int wv = t >> 6; s_red[wv][0] = z0; s_red[wv][1] = z1; s_red[wv][2] = z2; }
        __syncthreads();
        z0 = s_red[0][0] + s_red[1][0] + s_red[2][0] + s_red[3][0];
        z1 = s_red[0][1] + s_red[1][1] + s_red[2][1] + s_red[3][1];
        z2 = s_red[0][2] + s_red[1][2] + s_red[2][2] + s_red[3][2];
        __syncthreads();
        const float inv0 = 1.0f / z0, inv1 = 1.0f / z1, inv2 = 1.0f / z2;

        for (int base = 0; base < deg; base += MAXC) {
            int cn = min(MAXC, deg - base);
            for (int i = t; i < cn; i += 256) {
                int e = eidx[beg + base + i]; int s = src[e];
                float v0 = el[s * NH + 0] + er0; v0 = v0 > 0.f ? v0 : 0.2f * v0;
                float v1 = el[s * NH + 1] + er1; v1 = v1 > 0.f ? v1 : 0.2f * v1;
                float v2 = el[s * NH + 2] + er2; v2 = v2 > 0.f ? v2 : 0.2f * v2;
                s_alpha[i][0] = expf(v0 - m0) * inv0;
                s_alpha[i][1] = expf(v1 - m1) * inv1;
                s_alpha[i][2] = expf(v2 - m2) * inv2;
                s_src[i] = s;
            }
            __syncthreads();
            for (int i = 0; i < cn; i++) {
                int s = s_src[i];
                float c0 = s_alpha[i][0], c1 = s_alpha[i][1], c2 = s_alpha[i][2];
                uint2 xv = *(const uint2*)(xHL + (size_t)s * NINP + 2 * t);
                float x0 = bf2f((unsigned short)xv.x) + bf2f((unsigned short)(xv.x >> 16));
                float x1 = bf2f((unsigned short)xv.y) + bf2f((unsigned short)(xv.y >> 16));
                a00 = fmaf(c0, x0, a00); a01 = fmaf(c0, x1, a01);
                a10 = fmaf(c1, x0, a10); a11 = fmaf(c1, x1, a11);
                a20 = fmaf(c2, x0, a20); a21 = fmaf(c2, x1, a21);
            }
            __syncthreads();
        }
    }

    size_t b = (size_t)n * (NH * NINP) + 2 * t;
    store2(aggH, aggL, b,             a00, a01);
    store2(aggH, aggL, b + NINP,      a10, a11);
    store2(aggH, aggL, b + 2 * NINP,  a20, a21);
}

// ---------------------------------------------------------------------------
extern "C" void kernel_launch(void* const* d_in, const int* in_sizes, int n_in,
                              void* d_out, int out_size, void* d_ws, size_t ws_size,
                              hipStream_t stream)
{
    const float* emb_api  = (const float*)d_in[0];
    const float* emb_file = (const float*)d_in[1];
    // d_in[2] (e_tensor) unused by the reference
    const int*   src      = (const int*)d_in[3];
    const int*   dst      = (const int*)d_in[4];
    const float* Wapi     = (const float*)d_in[5];
    const float* bapi     = (const float*)d_in[6];
    const float* Wfile    = (const float*)d_in[7];
    const float* bfile    = (const float*)d_in[8];
    const float* Wsrc     = (const float*)d_in[9];
    const float* Wdst     = (const float*)d_in[10];
    const float* attn_l   = (const float*)d_in[11];
    const float* attn_r   = (const float*)d_in[12];
    const float* gat_bias = (const float*)d_in[13];
    const float* Whead    = (const float*)d_in[14];
    const float* bhead    = (const float*)d_in[15];

    const int n_api  = in_sizes[0] / NINP;   // 50000
    const int n_file = in_sizes[1] / NINP;   // 20000
    const int E      = in_sizes[2];          // 250000

    // ---- workspace carve-up ----
    char* p = (char*)d_ws;
    auto alloc = [&](size_t bytes) -> void* {
        void* r = (void*)p;
        p += (bytes + 255) & ~(size_t)255;
        return r;
    };

    unsigned int* xHL = (unsigned int*)alloc((size_t)n_api * NINP * 4);  // packed hi|lo

    // union: {Ahi,Alo} then {aggH,aggL} (disjoint lifetimes)
    size_t szA = (size_t)n_api  * NINP * 2;
    size_t szG = (size_t)n_file * NH * NINP * 2;
    size_t usz = 2 * szA; if (2 * szG > usz) usz = 2 * szG;
    char* U = (char*)alloc(usz);
    unsigned short* Ahi  = (unsigned short*)U;
    unsigned short* Alo  = (unsigned short*)(U + szA);
    unsigned short* aggH = (unsigned short*)U;
    unsigned short* aggL = (unsigned short*)(U + szG);

    unsigned short* WapiTh = (unsigned short*)alloc((size_t)NINP * NINP * 2);
    unsigned short* WapiTl = (unsigned short*)alloc((size_t)NINP * NINP * 2);
    unsigned short* WctH   = (unsigned short*)alloc((size_t)NOUT * NH * NINP * 2);
    unsigned short* WctL   = (unsigned short*)alloc((size_t)NOUT * NH * NINP * 2);
    float* el    = (float*)alloc((size_t)n_api  * NH * 4);
    float* er    = (float*)alloc((size_t)n_file * NH * 4);
    float* Wl2   = (float*)alloc((size_t)NINP * NH * 4);
    float* Wr2   = (float*)alloc((size_t)NINP * NH * 4);
    float* elc   = (float*)alloc(16);
    float* erc   = (float*)alloc(16);
    float* bias2 = (float*)alloc((size_t)NOUT * 4);
    int* cnt    = (int*)alloc((size_t)n_file * 4);
    int* rowptr = (int*)alloc((size_t)(n_file + 1) * 4);
    int* cursor = (int*)alloc((size_t)n_file * 4);
    int* eidx   = (int*)alloc((size_t)E * 4);

    float* out = (float*)d_out;

    // 1) weight prep
    make_attn_w<<<dim3(6), 256, 0, stream>>>(Wsrc, Wdst, attn_l, attn_r,
                                             Wapi, Wfile, bapi, bfile,
                                             Wl2, Wr2, elc, erc);
    make_wcomb_t<<<dim3(NINP, NH), 256, 0, stream>>>(Wsrc, Whead, gat_bias, bhead,
                                                     WctH, WctL, bias2);
    transpose_split<<<dim3(NINP / 32, NINP / 32), 256, 0, stream>>>(Wapi, WapiTh, WapiTl, NINP, NINP);

    // 2) CSR over dst (independent of the float pipeline)
    hipMemsetAsync(cnt, 0, sizeof(int) * n_file, stream);
    count_deg<<<dim3((E + 255) / 256), 256, 0, stream>>>(dst, cnt, E);
    scan_deg<<<1, 1024, 0, stream>>>(cnt, rowptr, cursor, n_file);
    fill_csr<<<dim3((E + 255) / 256), 256, 0, stream>>>(dst, cursor, eidx, E);

    // 3) emb streaming: split api to hi/lo + el; file only -> er
    split_el<true><<<dim3(2048), 256, 0, stream>>>(emb_api, Wl2, elc, Ahi, Alo, el, n_api);
    split_el<false><<<dim3(1024), 256, 0, stream>>>(emb_file, Wr2, erc, nullptr, nullptr, er, n_file);

    // 4) api projection -> packed hi|lo x features
    hgemm_split<NINP, true><<<dim3(NINP / 128, (n_api + 127) / 128), 256, 0, stream>>>(
        Ahi, Alo, WapiTh, WapiTl, bapi, xHL, n_api, NINP);

    // 5) edge softmax + aggregation (emits split-bf16 agg)
    gat_agg<<<dim3(n_file), 256, 0, stream>>>(rowptr, eidx, src, el, er, xHL, aggH, aggL);

    // 6) z = agg[20000,1536] @ Wcomb[1536,256] + bias2
    hgemm_split<NH * NINP, false><<<dim3(NOUT / 128, (n_file + 127) / 128), 256, 0, stream>>>(
        aggH, aggL, WctH, WctL, bias2, out, n_file, NOUT);
}

// Round 5
// 629.635 us; speedup vs baseline: 1.9985x; 1.0958x over previous
//
#include <hip/hip_runtime.h>
#include <hip/hip_bf16.h>
#include <math.h>

// Problem constants (fixed by the reference)
#define NINP 512
#define NOUT 256
#define NH   3
#define HD   768   // NH*NOUT

typedef short bf8 __attribute__((ext_vector_type(8)));     // 8 bf16 in 4 VGPRs
typedef float f32x4 __attribute__((ext_vector_type(4)));

// ---- bf16 split helpers (manual RN-even) ----
__device__ __forceinline__ unsigned short f2bf(float f) {
    unsigned int u = __float_as_uint(f);
    unsigned int r = (u + 0x7fffu + ((u >> 16) & 1u)) >> 16;
    return (unsigned short)r;
}
__device__ __forceinline__ float bf2f(unsigned short u) {
    return __uint_as_float(((unsigned int)u) << 16);
}

// async global->LDS, 16B per lane
__device__ __forceinline__ void gload16(const void* g, void* l) {
    __builtin_amdgcn_global_load_lds(
        (const void __attribute__((address_space(1)))*)g,
        (void __attribute__((address_space(3)))*)l, 16, 0, 0);
}

// ---------------------------------------------------------------------------
// make_attn_w: 6 blocks (side l/r x head h).
//   wl[j]   = sum_d Wgat[j, h*256+d] * attn[h,d]
//   W2[k,h] = sum_j Wproj[k,j] * wl[j]     -> el = emb @ W2 + cvec
//   cvec[h] = sum_j bproj[j] * wl[j]
// ---------------------------------------------------------------------------
__global__ __launch_bounds__(256)
void make_attn_w(const float* __restrict__ Wsrc, const float* __restrict__ Wdst,
                 const float* __restrict__ attn_l, const float* __restrict__ attn_r,
                 const float* __restrict__ Wapi, const float* __restrict__ Wfile,
                 const float* __restrict__ bapi, const float* __restrict__ bfile,
                 float* __restrict__ Wl2, float* __restrict__ Wr2,
                 float* __restrict__ elc, float* __restrict__ erc)
{
    __shared__ float wl[NINP];
    __shared__ float red[256];
    int b = blockIdx.x;
    int side = (b >= NH) ? 1 : 0;
    int h = b - side * NH;
    const float* Wg = side ? Wdst : Wsrc;
    const float* av = side ? attn_r : attn_l;
    const float* Wp = side ? Wfile : Wapi;
    const float* bp = side ? bfile : bapi;
    float* W2 = side ? Wr2 : Wl2;
    float* cv = side ? erc : elc;
    int t = threadIdx.x;

#pragma unroll
    for (int rep = 0; rep < 2; rep++) {
        int j = t + rep * 256;
        const float* wr = Wg + (size_t)j * HD + h * NOUT;
        const float* ar = av + h * NOUT;
        float s = 0.f;
        for (int d = 0; d < NOUT; d++) s = fmaf(wr[d], ar[d], s);
        wl[j] = s;
    }
    __syncthreads();

#pragma unroll
    for (int rep = 0; rep < 2; rep++) {
        int k = t + rep * 256;
        const float* pr = Wp + (size_t)k * NINP;
        float s = 0.f;
        for (int j = 0; j < NINP; j++) s = fmaf(pr[j], wl[j], s);
        W2[k * NH + h] = s;
    }
    float sb = fmaf(bp[t], wl[t], bp[t + 256] * wl[t + 256]);
    red[t] = sb;
    __syncthreads();
    for (int o = 128; o > 0; o >>= 1) {
        if (t < o) red[t] += red[t + o];
        __syncthreads();
    }
    if (t == 0) cv[h] = red[0];
}

// ---------------------------------------------------------------------------
// WcombT[h][c][k] = sum_d Wsrc[k, h*256+d] * Whead[h*256+d, c]   (fp32)
// grid (128, 3), 256 threads (c), 4 k-rows per block.
// ---------------------------------------------------------------------------
__global__ __launch_bounds__(256)
void make_wcomb(const float* __restrict__ Wsrc, const float* __restrict__ Whead,
                float* __restrict__ WcombT)
{
    __shared__ float s_w[4][256];
    int c = threadIdx.x;
    int k0 = blockIdx.x * 4;
    int h = blockIdx.y;
#pragma unroll
    for (int r = 0; r < 4; r++)
        s_w[r][c] = Wsrc[(size_t)(k0 + r) * HD + h * NOUT + c];
    __syncthreads();
    float acc[4] = {0.f, 0.f, 0.f, 0.f};
    for (int d = 0; d < NOUT; d++) {
        float wh = Whead[(size_t)(h * NOUT + d) * NOUT + c];
#pragma unroll
        for (int r = 0; r < 4; r++) acc[r] = fmaf(s_w[r][d], wh, acc[r]);
    }
#pragma unroll
    for (int r = 0; r < 4; r++)
        WcombT[((size_t)h * NOUT + c) * NINP + k0 + r] = acc[r];
}

// ---------------------------------------------------------------------------
// WfT[c][h*512 + j] = sum_k Wapi[j,k] * WcombT[h][c][k]   (split bf16)
// grid (64, 3), 256 threads (c), 8 j-rows per block.
// ---------------------------------------------------------------------------
__global__ __launch_bounds__(256)
void make_wfull(const float* __restrict__ Wapi, const float* __restrict__ WcombT,
                unsigned short* __restrict__ WfTh, unsigned short* __restrict__ WfTl)
{
    __shared__ float s_a[8][NINP];   // 16 KB
    int c = threadIdx.x;
    int j0 = blockIdx.x * 8;
    int h = blockIdx.y;
#pragma unroll
    for (int r = 0; r < 8; r++)
        for (int q = c; q < NINP; q += 256)
            s_a[r][q] = Wapi[(size_t)(j0 + r) * NINP + q];
    __syncthreads();
    float acc[8] = {};
    const float* wct = WcombT + ((size_t)h * NOUT + c) * NINP;
    for (int k4 = 0; k4 < NINP; k4 += 4) {
        float4 wv = *(const float4*)(wct + k4);
#pragma unroll
        for (int r = 0; r < 8; r++) {
            acc[r] = fmaf(s_a[r][k4 + 0], wv.x, acc[r]);
            acc[r] = fmaf(s_a[r][k4 + 1], wv.y, acc[r]);
            acc[r] = fmaf(s_a[r][k4 + 2], wv.z, acc[r]);
            acc[r] = fmaf(s_a[r][k4 + 3], wv.w, acc[r]);
        }
    }
#pragma unroll
    for (int r = 0; r < 8; r++) {
        size_t o = (size_t)c * (NH * NINP) + (size_t)h * NINP + j0 + r;
        unsigned short hv = f2bf(acc[r]);
        WfTh[o] = hv;
        WfTl[o] = f2bf(acc[r] - bf2f(hv));
    }
}

// ---------------------------------------------------------------------------
// bias0[c] = bhead[c] + sum_i gat_bias[i]*Whead[i,c]            (deg==0 rows)
// biasD[c] = bias0[c] + sum_h sum_k bapi[k]*WcombT[h][c][k]     (deg>0 rows)
// ---------------------------------------------------------------------------
__global__ void make_bias(const float* __restrict__ gat_bias, const float* __restrict__ Whead,
                          const float* __restrict__ bhead, const float* __restrict__ bapi,
                          const float* __restrict__ WcombT,
                          float* __restrict__ bias0, float* __restrict__ biasD)
{
    int c = threadIdx.x;
    float b0 = bhead[c];
    for (int i = 0; i < HD; i++)
        b0 = fmaf(gat_bias[i], Whead[(size_t)i * NOUT + c], b0);
    float bd = b0;
    for (int h = 0; h < NH; h++) {
        const float* wct = WcombT + ((size_t)h * NOUT + c) * NINP;
        for (int k = 0; k < NINP; k++) bd = fmaf(bapi[k], wct[k], bd);
    }
    bias0[c] = b0;
    biasD[c] = bd;
}

// ---------------------------------------------------------------------------
// node_el: one wave per row of emb[M][512]; el[row,h] = row.W2[:,h] + cvec[h]
// ---------------------------------------------------------------------------
__global__ __launch_bounds__(256)
void node_el(const float* __restrict__ emb, const float* __restrict__ W2,
             const float* __restrict__ cvec, float* __restrict__ elout, int M)
{
    const int lane = threadIdx.x & 63;
    const int k0 = lane * 8;
    float w[8][3];
#pragma unroll
    for (int j = 0; j < 8; j++)
#pragma unroll
        for (int h = 0; h < NH; h++)
            w[j][h] = W2[(k0 + j) * NH + h];
    const float c0 = cvec[0], c1 = cvec[1], c2 = cvec[2];

    int wid = blockIdx.x * 4 + (threadIdx.x >> 6);
    int nw = gridDim.x * 4;
    for (int row = wid; row < M; row += nw) {
        const float* r = emb + (size_t)row * NINP + k0;
        float4 v0 = *(const float4*)r;
        float4 v1 = *(const float4*)(r + 4);
        float x[8] = {v0.x, v0.y, v0.z, v0.w, v1.x, v1.y, v1.z, v1.w};
        float s0 = 0.f, s1 = 0.f, s2 = 0.f;
#pragma unroll
        for (int j = 0; j < 8; j++) {
            s0 = fmaf(x[j], w[j][0], s0);
            s1 = fmaf(x[j], w[j][1], s1);
            s2 = fmaf(x[j], w[j][2], s2);
        }
        for (int o = 32; o > 0; o >>= 1) {
            s0 += __shfl_xor(s0, o);
            s1 += __shfl_xor(s1, o);
            s2 += __shfl_xor(s2, o);
        }
        if (lane == 0) {
            elout[row * NH + 0] = s0 + c0;
            elout[row * NH + 1] = s1 + c1;
            elout[row * NH + 2] = s2 + c2;
        }
    }
}

// ---------------------------------------------------------------------------
// CSR build
// ---------------------------------------------------------------------------
__global__ void count_deg(const int* __restrict__ dst, int* __restrict__ cnt, int E)
{
    int t = blockIdx.x * blockDim.x + threadIdx.x;
    if (t < E) atomicAdd(&cnt[dst[t]], 1);
}

__global__ __launch_bounds__(1024)
void scan_deg(const int* __restrict__ cnt, int* __restrict__ rowptr,
              int* __restrict__ cursor, int n)
{
    __shared__ int wsum[16];
    __shared__ int s_carry;
    int tid = threadIdx.x;
    int lane = tid & 63, wid = tid >> 6;
    if (tid == 0) { rowptr[0] = 0; s_carry = 0; }
    __syncthreads();
    for (int base = 0; base < n; base += 1024) {
        int i = base + tid;
        int v = (i < n) ? cnt[i] : 0;
        int s = v;
#pragma unroll
        for (int o = 1; o < 64; o <<= 1) {
            int u = __shfl_up(s, o);
            if (lane >= o) s += u;
        }
        if (lane == 63) wsum[wid] = s;
        __syncthreads();
        if (wid == 0) {
            int ws = (lane < 16) ? wsum[lane] : 0;
#pragma unroll
            for (int o = 1; o < 16; o <<= 1) {
                int u = __shfl_up(ws, o);
                if (lane >= o) ws += u;
            }
            if (lane < 16) wsum[lane] = ws;
        }
        __syncthreads();
        int carry = s_carry;
        int incl = carry + (wid ? wsum[wid - 1] : 0) + s;
        if (i < n) {
            rowptr[i + 1] = incl;
            cursor[i] = incl - v;
        }
        __syncthreads();
        if (tid == 1023) s_carry = incl;
        __syncthreads();
    }
}

__global__ void fill_csr(const int* __restrict__ dst, int* __restrict__ cursor,
                         int* __restrict__ eidx, int E)
{
    int t = blockIdx.x * blockDim.x + threadIdx.x;
    if (t < E) {
        int p = atomicAdd(&cursor[dst[t]], 1);
        eidx[p] = t;
    }
}

// ---------------------------------------------------------------------------
// Per-dst-node edge softmax + aggregation of RAW emb_api rows (fp32);
// emits aggE as split bf16 hi/lo [n][h*512+k].
// ---------------------------------------------------------------------------
__device__ __forceinline__ void store2(unsigned short* hi, unsigned short* lo,
                                       size_t off, float v0, float v1)
{
    unsigned short h0 = f2bf(v0), h1 = f2bf(v1);
    unsigned short l0 = f2bf(v0 - bf2f(h0)), l1 = f2bf(v1 - bf2f(h1));
    *(unsigned int*)(hi + off) = (unsigned int)h0 | ((unsigned int)h1 << 16);
    *(unsigned int*)(lo + off) = (unsigned int)l0 | ((unsigned int)l1 << 16);
}

#define MAXC 256
__global__ __launch_bounds__(256)
void gat_agg(const int* __restrict__ rowptr, const int* __restrict__ eidx,
             const int* __restrict__ src,
             const float* __restrict__ el, const float* __restrict__ er,
             const float* __restrict__ x,
             unsigned short* __restrict__ aggH, unsigned short* __restrict__ aggL)
{
    int n = blockIdx.x;
    int t = threadIdx.x;
    int beg = rowptr[n], end = rowptr[n + 1];
    int deg = end - beg;

    __shared__ float s_red[4][3];
    __shared__ float s_alpha[MAXC][3];
    __shared__ int   s_src[MAXC];

    float a00 = 0.f, a01 = 0.f, a10 = 0.f, a11 = 0.f, a20 = 0.f, a21 = 0.f;

    if (deg > 0) {
        const float er0 = er[n * NH + 0], er1 = er[n * NH + 1], er2 = er[n * NH + 2];

        float m0 = -1e30f, m1 = -1e30f, m2 = -1e30f;
        for (int i = t; i < deg; i += 256) {
            int e = eidx[beg + i]; int s = src[e];
            float v0 = el[s * NH + 0] + er0; v0 = v0 > 0.f ? v0 : 0.2f * v0;
            float v1 = el[s * NH + 1] + er1; v1 = v1 > 0.f ? v1 : 0.2f * v1;
            float v2 = el[s * NH + 2] + er2; v2 = v2 > 0.f ? v2 : 0.2f * v2;
            m0 = fmaxf(m0, v0); m1 = fmaxf(m1, v1); m2 = fmaxf(m2, v2);
        }
        for (int o = 32; o > 0; o >>= 1) {
            m0 = fmaxf(m0, __shfl_xor(m0, o));
            m1 = fmaxf(m1, __shfl_xor(m1, o));
            m2 = fmaxf(m2, __shfl_xor(m2, o));
        }
        if ((t & 63) == 0) { int wv = t >> 6; s_red[wv][0] = m0; s_red[wv][1] = m1; s_red[wv][2] = m2; }
        __syncthreads();
        m0 = fmaxf(fmaxf(s_red[0][0], s_red[1][0]), fmaxf(s_red[2][0], s_red[3][0]));
        m1 = fmaxf(fmaxf(s_red[0][1], s_red[1][1]), fmaxf(s_red[2][1], s_red[3][1]));
        m2 = fmaxf(fmaxf(s_red[0][2], s_red[1][2]), fmaxf(s_red[2][2], s_red[3][2]));
        __syncthreads();

        float z0 = 0.f, z1 = 0.f, z2 = 0.f;
        for (int i = t; i < deg; i += 256) {
            int e = eidx[beg + i]; int s = src[e];
            float v0 = el[s * NH + 0] + er0; v0 = v0 > 0.f ? v0 : 0.2f * v0;
            float v1 = el[s * NH + 1] + er1; v1 = v1 > 0.f ? v1 : 0.2f * v1;
            float v2 = el[s * NH + 2] + er2; v2 = v2 > 0.f ? v2 : 0.2f * v2;
            z0 += expf(v0 - m0); z1 += expf(v1 - m1); z2 += expf(v2 - m2);
        }
        for (int o = 32; o > 0; o >>= 1) {
            z0 += __shfl_xor(z0, o); z1 += __shfl_xor(z1, o); z2 += __shfl_xor(z2, o);
        }
        if ((t & 63) == 0) { int wv = t >> 6; s_red[wv][0] = z0; s_red[wv][1] = z1; s_red[wv][2] = z2; }
        __syncthreads();
        z0 = s_red[0][0] + s_red[1][0] + s_red[2][0] + s_red[3][0];
        z1 = s_red[0][1] + s_red[1][1] + s_red[2][1] + s_red[3][1];
        z2 = s_red[0][2] + s_red[1][2] + s_red[2][2] + s_red[3][2];
        __syncthreads();
        const float inv0 = 1.0f / z0, inv1 = 1.0f / z1, inv2 = 1.0f / z2;

        for (int base = 0; base < deg; base += MAXC) {
            int cn = min(MAXC, deg - base);
            for (int i = t; i < cn; i += 256) {
                int e = eidx[beg + base + i]; int s = src[e];
                float v0 = el[s * NH + 0] + er0; v0 = v0 > 0.f ? v0 : 0.2f * v0;
                float v1 = el[s * NH + 1] + er1; v1 = v1 > 0.f ? v1 : 0.2f * v1;
                float v2 = el[s * NH + 2] + er2; v2 = v2 > 0.f ? v2 : 0.2f * v2;
                s_alpha[i][0] = expf(v0 - m0) * inv0;
                s_alpha[i][1] = expf(v1 - m1) * inv1;
                s_alpha[i][2] = expf(v2 - m2) * inv2;
                s_src[i] = s;
            }
            __syncthreads();
            // aggregation, 4 edges per step (4 gathers in flight)
            int i = 0;
            for (; i + 4 <= cn; i += 4) {
                int sa = s_src[i], sb = s_src[i + 1], sc = s_src[i + 2], sd = s_src[i + 3];
                float2 xa = *(const float2*)(x + (size_t)sa * NINP + 2 * t);
                float2 xb = *(const float2*)(x + (size_t)sb * NINP + 2 * t);
                float2 xc = *(const float2*)(x + (size_t)sc * NINP + 2 * t);
                float2 xd = *(const float2*)(x + (size_t)sd * NINP + 2 * t);
#pragma unroll
                for (int q = 0; q < 4; q++) {
                    float2 xv = q == 0 ? xa : (q == 1 ? xb : (q == 2 ? xc : xd));
                    float c0 = s_alpha[i + q][0], c1 = s_alpha[i + q][1], c2 = s_alpha[i + q][2];
                    a00 = fmaf(c0, xv.x, a00); a01 = fmaf(c0, xv.y, a01);
                    a10 = fmaf(c1, xv.x, a10); a11 = fmaf(c1, xv.y, a11);
                    a20 = fmaf(c2, xv.x, a20); a21 = fmaf(c2, xv.y, a21);
                }
            }
            for (; i < cn; i++) {
                int s = s_src[i];
                float c0 = s_alpha[i][0], c1 = s_alpha[i][1], c2 = s_alpha[i][2];
                float2 xv = *(const float2*)(x + (size_t)s * NINP + 2 * t);
                a00 = fmaf(c0, xv.x, a00); a01 = fmaf(c0, xv.y, a01);
                a10 = fmaf(c1, xv.x, a10); a11 = fmaf(c1, xv.y, a11);
                a20 = fmaf(c2, xv.x, a20); a21 = fmaf(c2, xv.y, a21);
            }
            __syncthreads();
        }
    }

    size_t b = (size_t)n * (NH * NINP) + 2 * t;
    store2(aggH, aggL, b,             a00, a01);
    store2(aggH, aggL, b + NINP,      a10, a11);
    store2(aggH, aggL, b + 2 * NINP,  a20, a21);
}

// ---------------------------------------------------------------------------
// 2-phase double-buffered split-bf16 MFMA GEMM:
//   C[M,N] = (Ah+Al)[M,K] @ (Bh+Bl)[N,K]^T + (deg>0 ? biasD : bias0)
// 128x128 tile, 4 waves, 4x4 frags of mfma_f32_16x16x32_bf16, 3 passes
// (hh+hl+lh).  T3-minimum pipeline: stage(k+1) -> compute(k) -> barrier.
// LDS 2 x 32KB; chunk swizzle c ^= (r>>1)&3 via pre-swizzled global src.
// Bijective XCD-chunked block swizzle for L2 reuse.
// ---------------------------------------------------------------------------
template<int K>
__global__ __launch_bounds__(256)
void hgemm2(const unsigned short* __restrict__ Ah, const unsigned short* __restrict__ Al,
            const unsigned short* __restrict__ Bh, const unsigned short* __restrict__ Bl,
            const float* __restrict__ biasD, const float* __restrict__ bias0,
            const int* __restrict__ rowptr,
            float* __restrict__ C, int M, int N)
{
    __shared__ __align__(16) unsigned short sA[2][2][4096];  // [buf][hi/lo][128*32]
    __shared__ __align__(16) unsigned short sB[2][2][4096];

    const int nwg = gridDim.x * gridDim.y;
    int flat = blockIdx.y * gridDim.x + blockIdx.x;
    {
        const int q = nwg >> 3, rr = nwg & 7;
        int xcd = flat & 7, idx = flat >> 3;
        flat = (xcd < rr) ? (xcd * (q + 1) + idx)
                          : (rr * (q + 1) + (xcd - rr) * q + idx);
    }
    const int row0 = (flat / gridDim.x) * 128;
    const int col0 = (flat % gridDim.x) * 128;

    const int tid  = threadIdx.x;
    const int lane = tid & 63;
    const int w    = tid >> 6;
    const int wr   = w >> 1, wc = w & 1;

    // staging: wave w covers 16B-chunks i = w*128 + {0,64} + lane
    int i0 = w * 128 + lane;
    int r0s = i0 >> 2, c0s = i0 & 3;
    int i1 = i0 + 64;
    int r1s = i1 >> 2, c1s = i1 & 3;
    int ar0 = row0 + r0s; if (ar0 >= M) ar0 = M - 1;
    int ar1 = row0 + r1s; if (ar1 >= M) ar1 = M - 1;
    const size_t offA0 = (size_t)ar0 * K + (size_t)((c0s ^ ((r0s >> 1) & 3)) * 8);
    const size_t offA1 = (size_t)ar1 * K + (size_t)((c1s ^ ((r1s >> 1) & 3)) * 8);
    const size_t offB0 = (size_t)(col0 + r0s) * K + (size_t)((c0s ^ ((r0s >> 1) & 3)) * 8);
    const size_t offB1 = (size_t)(col0 + r1s) * K + (size_t)((c1s ^ ((r1s >> 1) & 3)) * 8);
    const int d0 = w * 1024;       // wave-uniform LDS chunk base (shorts)
    const int d1 = d0 + 512;

    // fragment ds_read offsets: chunk = fg ^ ((r>>1)&3)
    const int fg = lane >> 4, fr = lane & 15;
    int aoff[4], boff[4];
#pragma unroll
    for (int mi = 0; mi < 4; mi++) {
        int r = wr * 64 + mi * 16 + fr;
        aoff[mi] = r * 32 + ((fg ^ ((r >> 1) & 3)) * 8);
    }
#pragma unroll
    for (int ni = 0; ni < 4; ni++) {
        int r = wc * 64 + ni * 16 + fr;
        boff[ni] = r * 32 + ((fg ^ ((r >> 1) & 3)) * 8);
    }

    auto STAGE = [&](int bf, int kof) {
        gload16(Ah + offA0 + kof, &sA[bf][0][d0]);
        gload16(Ah + offA1 + kof, &sA[bf][0][d1]);
        gload16(Al + offA0 + kof, &sA[bf][1][d0]);
        gload16(Al + offA1 + kof, &sA[bf][1][d1]);
        gload16(Bh + offB0 + kof, &sB[bf][0][d0]);
        gload16(Bh + offB1 + kof, &sB[bf][0][d1]);
        gload16(Bl + offB0 + kof, &sB[bf][1][d0]);
        gload16(Bl + offB1 + kof, &sB[bf][1][d1]);
    };

    f32x4 acc[4][4];
#pragma unroll
    for (int mi = 0; mi < 4; mi++)
#pragma unroll
        for (int ni = 0; ni < 4; ni++)
            acc[mi][ni] = (f32x4){0.f, 0.f, 0.f, 0.f};

    const int NT = K / 32;
    STAGE(0, 0);
    __syncthreads();
    for (int kt = 0; kt < NT; kt++) {
        const int cur = kt & 1;
        if (kt + 1 < NT) STAGE(cur ^ 1, (kt + 1) * 32);   // prefetch next tile

        bf8 a[4][2], b[4][2];
#pragma unroll
        for (int mi = 0; mi < 4; mi++) {
            a[mi][0] = *(const bf8*)&sA[cur][0][aoff[mi]];
            a[mi][1] = *(const bf8*)&sA[cur][1][aoff[mi]];
        }
#pragma unroll
        for (int ni = 0; ni < 4; ni++) {
            b[ni][0] = *(const bf8*)&sB[cur][0][boff[ni]];
            b[ni][1] = *(const bf8*)&sB[cur][1][boff[ni]];
        }
#pragma unroll
        for (int mi = 0; mi < 4; mi++)
#pragma unroll
            for (int ni = 0; ni < 4; ni++)
                acc[mi][ni] = __builtin_amdgcn_mfma_f32_16x16x32_bf16(a[mi][0], b[ni][0], acc[mi][ni], 0, 0, 0);
#pragma unroll
        for (int mi = 0; mi < 4; mi++)
#pragma unroll
            for (int ni = 0; ni < 4; ni++)
                acc[mi][ni] = __builtin_amdgcn_mfma_f32_16x16x32_bf16(a[mi][0], b[ni][1], acc[mi][ni], 0, 0, 0);
#pragma unroll
        for (int mi = 0; mi < 4; mi++)
#pragma unroll
            for (int ni = 0; ni < 4; ni++)
                acc[mi][ni] = __builtin_amdgcn_mfma_f32_16x16x32_bf16(a[mi][1], b[ni][0], acc[mi][ni], 0, 0, 0);
        __syncthreads();   // publishes prefetched buf, protects cur for re-stage
    }

    // epilogue: C/D layout col=lane&15, row=(lane>>4)*4+reg  [verified m89]
#pragma unroll
    for (int mi = 0; mi < 4; mi++) {
        int rb = row0 + wr * 64 + mi * 16 + fg * 4;
        bool dpos[4];
#pragma unroll
        for (int j = 0; j < 4; j++) {
            int r = rb + j;
            dpos[j] = (r < M) ? (rowptr[r + 1] > rowptr[r]) : false;
        }
#pragma unroll
        for (int ni = 0; ni < 4; ni++) {
            int col = col0 + wc * 64 + ni * 16 + fr;
            float bD = biasD[col], b0 = bias0[col];
#pragma unroll
            for (int j = 0; j < 4; j++) {
                int r = rb + j;
                if (r < M)
                    C[(size_t)r * N + col] = acc[mi][ni][j] + (dpos[j] ? bD : b0);
            }
        }
    }
}

// ---------------------------------------------------------------------------
extern "C" void kernel_launch(void* const* d_in, const int* in_sizes, int n_in,
                              void* d_out, int out_size, void* d_ws, size_t ws_size,
                              hipStream_t stream)
{
    const float* emb_api  = (const float*)d_in[0];
    const float* emb_file = (const float*)d_in[1];
    // d_in[2] (e_tensor) unused by the reference
    const int*   src      = (const int*)d_in[3];
    const int*   dst      = (const int*)d_in[4];
    const float* Wapi     = (const float*)d_in[5];
    const float* bapi     = (const float*)d_in[6];
    const float* Wfile    = (const float*)d_in[7];
    const float* bfile    = (const float*)d_in[8];
    const float* Wsrc     = (const float*)d_in[9];
    const float* Wdst     = (const float*)d_in[10];
    const float* attn_l   = (const float*)d_in[11];
    const float* attn_r   = (const float*)d_in[12];
    const float* gat_bias = (const float*)d_in[13];
    const float* Whead    = (const float*)d_in[14];
    const float* bhead    = (const float*)d_in[15];

    const int n_api  = in_sizes[0] / NINP;   // 50000
    const int n_file = in_sizes[1] / NINP;   // 20000
    const int E      = in_sizes[2];          // 250000

    // ---- workspace carve-up ----
    char* p = (char*)d_ws;
    auto alloc = [&](size_t bytes) -> void* {
        void* r = (void*)p;
        p += (bytes + 255) & ~(size_t)255;
        return r;
    };

    size_t szG = (size_t)n_file * NH * NINP * 2;
    unsigned short* aggH = (unsigned short*)alloc(szG);
    unsigned short* aggL = (unsigned short*)alloc(szG);
    float* WcombT = (float*)alloc((size_t)NH * NOUT * NINP * 4);
    unsigned short* WfTh = (unsigned short*)alloc((size_t)NOUT * NH * NINP * 2);
    unsigned short* WfTl = (unsigned short*)alloc((size_t)NOUT * NH * NINP * 2);
    float* el    = (float*)alloc((size_t)n_api  * NH * 4);
    float* er    = (float*)alloc((size_t)n_file * NH * 4);
    float* Wl2   = (float*)alloc((size_t)NINP * NH * 4);
    float* Wr2   = (float*)alloc((size_t)NINP * NH * 4);
    float* elc   = (float*)alloc(16);
    float* erc   = (float*)alloc(16);
    float* bias0 = (float*)alloc((size_t)NOUT * 4);
    float* biasD = (float*)alloc((size_t)NOUT * 4);
    int* cnt    = (int*)alloc((size_t)n_file * 4);
    int* rowptr = (int*)alloc((size_t)(n_file + 1) * 4);
    int* cursor = (int*)alloc((size_t)n_file * 4);
    int* eidx   = (int*)alloc((size_t)E * 4);

    float* out = (float*)d_out;

    // 1) weight prep (all small)
    make_attn_w<<<dim3(6), 256, 0, stream>>>(Wsrc, Wdst, attn_l, attn_r,
                                             Wapi, Wfile, bapi, bfile,
                                             Wl2, Wr2, elc, erc);
    make_wcomb<<<dim3(NINP / 4, NH), 256, 0, stream>>>(Wsrc, Whead, WcombT);
    make_wfull<<<dim3(NINP / 8, NH), 256, 0, stream>>>(Wapi, WcombT, WfTh, WfTl);
    make_bias<<<1, 256, 0, stream>>>(gat_bias, Whead, bhead, bapi, WcombT, bias0, biasD);

    // 2) CSR over dst
    hipMemsetAsync(cnt, 0, sizeof(int) * n_file, stream);
    count_deg<<<dim3((E + 255) / 256), 256, 0, stream>>>(dst, cnt, E);
    scan_deg<<<1, 1024, 0, stream>>>(cnt, rowptr, cursor, n_file);
    fill_csr<<<dim3((E + 255) / 256), 256, 0, stream>>>(dst, cursor, eidx, E);

    // 3) node attention logits (no projection needed — folded into W2)
    node_el<<<dim3(2048), 256, 0, stream>>>(emb_api, Wl2, elc, el, n_api);
    node_el<<<dim3(1024), 256, 0, stream>>>(emb_file, Wr2, erc, er, n_file);

    // 4) edge softmax + aggregation of raw emb rows -> split-bf16 aggE
    gat_agg<<<dim3(n_file), 256, 0, stream>>>(rowptr, eidx, src, el, er, emb_api, aggH, aggL);

    // 5) z = aggE[20000,1536] @ Wfull[1536,256] + bias(deg)
    hgemm2<NH * NINP><<<dim3(NOUT / 128, (n_file + 127) / 128), 256, 0, stream>>>(
        aggH, aggL, WfTh, WfTl, biasD, bias0, rowptr, out, n_file, NOUT);
}

// Round 6
// 475.277 us; speedup vs baseline: 2.6476x; 1.3248x over previous
//
#include <hip/hip_runtime.h>
#include <math.h>

// Problem constants (fixed by the reference)
#define NINP 512
#define NOUT 256
#define NH   3
#define HD   768   // NH*NOUT

typedef _Float16 f16x8 __attribute__((ext_vector_type(8)));
typedef float f32x4 __attribute__((ext_vector_type(4)));

// ---- fp16 helpers (RNE) ----
__device__ __forceinline__ unsigned short f2h(float f) {
    union { _Float16 h; unsigned short u; } c; c.h = (_Float16)f; return c.u;
}
__device__ __forceinline__ float h2f(unsigned short u) {
    union { _Float16 h; unsigned short u; } c; c.u = u; return (float)c.h;
}

// async global->LDS, 16B per lane
__device__ __forceinline__ void gload16(const void* g, void* l) {
    __builtin_amdgcn_global_load_lds(
        (const void __attribute__((address_space(1)))*)g,
        (void __attribute__((address_space(3)))*)l, 16, 0, 0);
}

// ---------------------------------------------------------------------------
// make_weights: ALL weight prep in one kernel (roles by blockIdx.x):
//  [0,192):  Wfull: WfT[c][h*512+j] = (Wapi @ Wsrc_h @ Whead_h)[j,c]  (fp16)
//  [192,198): attn fold: Wl2/Wr2 [512][3], elc/erc[3]
//  [198]:    bias0/biasD via pb[i] = bapi . Wsrc[:,i]
//  [199,278): zero cnt[20000]
// ---------------------------------------------------------------------------
#define MW_WF   192
#define MW_AT   198
#define MW_BI   199
#define MW_GRID 278
__global__ __launch_bounds__(256)
void make_weights(const float* __restrict__ Wsrc, const float* __restrict__ Wdst,
                  const float* __restrict__ attn_l, const float* __restrict__ attn_r,
                  const float* __restrict__ Wapi, const float* __restrict__ Wfile,
                  const float* __restrict__ bapi, const float* __restrict__ bfile,
                  const float* __restrict__ Whead, const float* __restrict__ gat_bias,
                  const float* __restrict__ bhead,
                  unsigned short* __restrict__ WfT,
                  float* __restrict__ Wl2, float* __restrict__ Wr2,
                  float* __restrict__ elc, float* __restrict__ erc,
                  float* __restrict__ bias0, float* __restrict__ biasD,
                  int* __restrict__ cnt, int n_file)
{
    __shared__ float sm[8 * NINP + 8 * NOUT];   // 24 KB, role-dependent reuse
    const int b = blockIdx.x, t = threadIdx.x;

    if (b < MW_WF) {
        // ---- Wfull block: j-tile (8 rows) x head h ----
        float* s_a = sm;              // [8][512] Wapi rows
        float* s_T = sm + 8 * NINP;   // [8][256] T = Wapi_rows @ Wsrc_h
        const int j0 = (b & 63) * 8, h = b >> 6;
#pragma unroll
        for (int r = 0; r < 8; r++)
            for (int q = t; q < NINP; q += 256)
                s_a[r * NINP + q] = Wapi[(size_t)(j0 + r) * NINP + q];
        __syncthreads();
        float tr[8] = {};
        for (int k = 0; k < NINP; k++) {
            float ws = Wsrc[(size_t)k * HD + h * NOUT + t];
#pragma unroll
            for (int r = 0; r < 8; r++) tr[r] = fmaf(s_a[r * NINP + k], ws, tr[r]);
        }
#pragma unroll
        for (int r = 0; r < 8; r++) s_T[r * NOUT + t] = tr[r];
        __syncthreads();
        float acc[8] = {};
        for (int d = 0; d < NOUT; d++) {
            float wh = Whead[(size_t)(h * NOUT + d) * NOUT + t];
#pragma unroll
            for (int r = 0; r < 8; r++) acc[r] = fmaf(s_T[r * NOUT + d], wh, acc[r]);
        }
        unsigned int p[4];
#pragma unroll
        for (int j = 0; j < 4; j++)
            p[j] = (unsigned int)f2h(acc[2 * j]) | ((unsigned int)f2h(acc[2 * j + 1]) << 16);
        *(uint4*)(WfT + (size_t)t * (NH * NINP) + h * NINP + j0) =
            make_uint4(p[0], p[1], p[2], p[3]);
    } else if (b < MW_AT) {
        // ---- attn fold block: side x head ----
        float* wl = sm;          // [512]
        float* red = sm + NINP;  // [256]
        int bb = b - MW_WF;
        int side = (bb >= NH) ? 1 : 0;
        int h = bb - side * NH;
        const float* Wg = side ? Wdst : Wsrc;
        const float* av = side ? attn_r : attn_l;
        const float* Wp = side ? Wfile : Wapi;
        const float* bp = side ? bfile : bapi;
        float* W2 = side ? Wr2 : Wl2;
        float* cv = side ? erc : elc;
#pragma unroll
        for (int rep = 0; rep < 2; rep++) {
            int j = t + rep * 256;
            const float* wr = Wg + (size_t)j * HD + h * NOUT;
            const float* ar = av + h * NOUT;
            float s = 0.f;
            for (int d = 0; d < NOUT; d++) s = fmaf(wr[d], ar[d], s);
            wl[j] = s;
        }
        __syncthreads();
#pragma unroll
        for (int rep = 0; rep < 2; rep++) {
            int k = t + rep * 256;
            const float* pr = Wp + (size_t)k * NINP;
            float s = 0.f;
            for (int j = 0; j < NINP; j++) s = fmaf(pr[j], wl[j], s);
            W2[k * NH + h] = s;
        }
        float sb = fmaf(bp[t], wl[t], bp[t + 256] * wl[t + 256]);
        red[t] = sb;
        __syncthreads();
        for (int o = 128; o > 0; o >>= 1) {
            if (t < o) red[t] += red[t + o];
            __syncthreads();
        }
        if (t == 0) cv[h] = red[0];
    } else if (b == MW_AT) {
        // ---- bias block: pb[i] = bapi . Wsrc[:,i]; then fold through Whead ----
        float* pb = sm;   // [768]
#pragma unroll
        for (int rep = 0; rep < 3; rep++) {
            int i = t + rep * 256;
            float s = 0.f;
            for (int k = 0; k < NINP; k++)
                s = fmaf(bapi[k], Wsrc[(size_t)k * HD + i], s);
            pb[i] = s;
        }
        __syncthreads();
        float b0 = bhead[t], bd = 0.f;
        for (int i = 0; i < HD; i++) {
            float wh = Whead[(size_t)i * NOUT + t];
            b0 = fmaf(gat_bias[i], wh, b0);
            bd = fmaf(pb[i], wh, bd);
        }
        bias0[t] = b0;
        biasD[t] = b0 + bd;
    } else {
        int idx = (b - MW_BI) * 256 + t;
        if (idx < n_file) cnt[idx] = 0;
    }
}

// ---------------------------------------------------------------------------
// node_el_both: roles by blockIdx.x:
//  [0,1024):    api rows — store fp16 copy + el = emb.Wl2 + elc
//  [1024,1536): file rows — er = emb.Wr2 + erc
//  [1536,...):  count_deg atomics (cnt pre-zeroed by make_weights)
// ---------------------------------------------------------------------------
#define NBA 1024
#define NBF 512
__global__ __launch_bounds__(256)
void node_el_both(const float* __restrict__ emb_api, const float* __restrict__ emb_file,
                  const float* __restrict__ Wl2, const float* __restrict__ Wr2,
                  const float* __restrict__ elc, const float* __restrict__ erc,
                  unsigned short* __restrict__ Af16,
                  float* __restrict__ el, float* __restrict__ er,
                  int n_api, int n_file,
                  const int* __restrict__ dst, int* __restrict__ cnt, int E)
{
    const int t = threadIdx.x;
    if (blockIdx.x >= NBA + NBF) {
        int i = (blockIdx.x - NBA - NBF) * 256 + t;
        if (i < E) atomicAdd(&cnt[dst[i]], 1);
        return;
    }
    const bool api = blockIdx.x < NBA;
    const float* emb = api ? emb_api : emb_file;
    const float* W2  = api ? Wl2 : Wr2;
    const float* cvp = api ? elc : erc;
    float* eo = api ? el : er;
    const int M = api ? n_api : n_file;
    const int b0 = api ? blockIdx.x : blockIdx.x - NBA;
    const int nb = api ? NBA : NBF;

    const int lane = t & 63;
    const int k0 = lane * 8;
    float w[8][3];
#pragma unroll
    for (int j = 0; j < 8; j++)
#pragma unroll
        for (int h = 0; h < NH; h++)
            w[j][h] = W2[(k0 + j) * NH + h];
    const float c0 = cvp[0], c1 = cvp[1], c2 = cvp[2];

    for (int row = b0 * 4 + (t >> 6); row < M; row += nb * 4) {
        const float* r = emb + (size_t)row * NINP + k0;
        float4 v0 = *(const float4*)r;
        float4 v1 = *(const float4*)(r + 4);
        float x[8] = {v0.x, v0.y, v0.z, v0.w, v1.x, v1.y, v1.z, v1.w};
        if (api) {
            unsigned int p[4];
#pragma unroll
            for (int j = 0; j < 4; j++)
                p[j] = (unsigned int)f2h(x[2 * j]) | ((unsigned int)f2h(x[2 * j + 1]) << 16);
            *(uint4*)(Af16 + (size_t)row * NINP + k0) = make_uint4(p[0], p[1], p[2], p[3]);
        }
        float s0 = 0.f, s1 = 0.f, s2 = 0.f;
#pragma unroll
        for (int j = 0; j < 8; j++) {
            s0 = fmaf(x[j], w[j][0], s0);
            s1 = fmaf(x[j], w[j][1], s1);
            s2 = fmaf(x[j], w[j][2], s2);
        }
        for (int o = 32; o > 0; o >>= 1) {
            s0 += __shfl_xor(s0, o);
            s1 += __shfl_xor(s1, o);
            s2 += __shfl_xor(s2, o);
        }
        if (lane == 0) {
            eo[row * NH + 0] = s0 + c0;
            eo[row * NH + 1] = s1 + c1;
            eo[row * NH + 2] = s2 + c2;
        }
    }
}

// ---------------------------------------------------------------------------
// CSR scan + fill
// ---------------------------------------------------------------------------
__global__ __launch_bounds__(1024)
void scan_deg(const int* __restrict__ cnt, int* __restrict__ rowptr,
              int* __restrict__ cursor, int n)
{
    __shared__ int wsum[16];
    __shared__ int s_carry;
    int tid = threadIdx.x;
    int lane = tid & 63, wid = tid >> 6;
    if (tid == 0) { rowptr[0] = 0; s_carry = 0; }
    __syncthreads();
    for (int base = 0; base < n; base += 1024) {
        int i = base + tid;
        int v = (i < n) ? cnt[i] : 0;
        int s = v;
#pragma unroll
        for (int o = 1; o < 64; o <<= 1) {
            int u = __shfl_up(s, o);
            if (lane >= o) s += u;
        }
        if (lane == 63) wsum[wid] = s;
        __syncthreads();
        if (wid == 0) {
            int ws = (lane < 16) ? wsum[lane] : 0;
#pragma unroll
            for (int o = 1; o < 16; o <<= 1) {
                int u = __shfl_up(ws, o);
                if (lane >= o) ws += u;
            }
            if (lane < 16) wsum[lane] = ws;
        }
        __syncthreads();
        int carry = s_carry;
        int incl = carry + (wid ? wsum[wid - 1] : 0) + s;
        if (i < n) {
            rowptr[i + 1] = incl;
            cursor[i] = incl - v;
        }
        __syncthreads();
        if (tid == 1023) s_carry = incl;
        __syncthreads();
    }
}

__global__ void fill_csr(const int* __restrict__ dst, int* __restrict__ cursor,
                         int* __restrict__ eidx, int E)
{
    int t = blockIdx.x * blockDim.x + threadIdx.x;
    if (t < E) {
        int p = atomicAdd(&cursor[dst[t]], 1);
        eidx[p] = t;
    }
}

// ---------------------------------------------------------------------------
// gat_agg: per-dst-node edge softmax + aggregation of fp16 emb rows.
// Fast path (deg<=256): ONE el-gather into regs, 2 reduce rounds.
// Output agg fp16 [n][h*512+k].
// ---------------------------------------------------------------------------
#define MAXC 256
__device__ __forceinline__ float lrelu(float v) { return v > 0.f ? v : 0.2f * v; }

__global__ __launch_bounds__(256)
void gat_agg(const int* __restrict__ rowptr, const int* __restrict__ eidx,
             const int* __restrict__ src,
             const float* __restrict__ el, const float* __restrict__ er,
             const unsigned short* __restrict__ x,
             unsigned short* __restrict__ agg)
{
    const int n = blockIdx.x;
    const int t = threadIdx.x;
    const int beg = rowptr[n], end = rowptr[n + 1];
    const int deg = end - beg;

    __shared__ float s_red[4][3];
    __shared__ float s_alpha[MAXC][3];
    __shared__ int   s_src[MAXC];

    float a00 = 0.f, a01 = 0.f, a10 = 0.f, a11 = 0.f, a20 = 0.f, a21 = 0.f;
    const int xoff = 2 * t;

    if (deg > 0) {
        const float er0 = er[n * NH + 0], er1 = er[n * NH + 1], er2 = er[n * NH + 2];

        if (deg <= MAXC) {
            // ---- fast path: one edge per thread, logits in registers ----
            float v0 = -1e30f, v1 = -1e30f, v2 = -1e30f;
            int s = 0;
            if (t < deg) {
                int e = eidx[beg + t]; s = src[e];
                v0 = lrelu(el[s * NH + 0] + er0);
                v1 = lrelu(el[s * NH + 1] + er1);
                v2 = lrelu(el[s * NH + 2] + er2);
            }
            float m0 = v0, m1 = v1, m2 = v2;
            for (int o = 32; o > 0; o >>= 1) {
                m0 = fmaxf(m0, __shfl_xor(m0, o));
                m1 = fmaxf(m1, __shfl_xor(m1, o));
                m2 = fmaxf(m2, __shfl_xor(m2, o));
            }
            if ((t & 63) == 0) { int wv = t >> 6; s_red[wv][0] = m0; s_red[wv][1] = m1; s_red[wv][2] = m2; }
            __syncthreads();
            m0 = fmaxf(fmaxf(s_red[0][0], s_red[1][0]), fmaxf(s_red[2][0], s_red[3][0]));
            m1 = fmaxf(fmaxf(s_red[0][1], s_red[1][1]), fmaxf(s_red[2][1], s_red[3][1]));
            m2 = fmaxf(fmaxf(s_red[0][2], s_red[1][2]), fmaxf(s_red[2][2], s_red[3][2]));
            __syncthreads();
            float e0 = (t < deg) ? expf(v0 - m0) : 0.f;
            float e1 = (t < deg) ? expf(v1 - m1) : 0.f;
            float e2 = (t < deg) ? expf(v2 - m2) : 0.f;
            float z0 = e0, z1 = e1, z2 = e2;
            for (int o = 32; o > 0; o >>= 1) {
                z0 += __shfl_xor(z0, o); z1 += __shfl_xor(z1, o); z2 += __shfl_xor(z2, o);
            }
            if ((t & 63) == 0) { int wv = t >> 6; s_red[wv][0] = z0; s_red[wv][1] = z1; s_red[wv][2] = z2; }
            __syncthreads();
            z0 = s_red[0][0] + s_red[1][0] + s_red[2][0] + s_red[3][0];
            z1 = s_red[0][1] + s_red[1][1] + s_red[2][1] + s_red[3][1];
            z2 = s_red[0][2] + s_red[1][2] + s_red[2][2] + s_red[3][2];
            if (t < deg) {
                s_alpha[t][0] = e0 / z0;
                s_alpha[t][1] = e1 / z1;
                s_alpha[t][2] = e2 / z2;
                s_src[t] = s;
            }
            __syncthreads();
            // ---- aggregation ----
            int i = 0;
            for (; i + 4 <= deg; i += 4) {
                int sa = s_src[i], sb = s_src[i + 1], sc = s_src[i + 2], sd = s_src[i + 3];
                unsigned int xa = *(const unsigned int*)(x + (size_t)sa * NINP + xoff);
                unsigned int xb = *(const unsigned int*)(x + (size_t)sb * NINP + xoff);
                unsigned int xc = *(const unsigned int*)(x + (size_t)sc * NINP + xoff);
                unsigned int xd = *(const unsigned int*)(x + (size_t)sd * NINP + xoff);
#pragma unroll
                for (int q = 0; q < 4; q++) {
                    unsigned int xv = q == 0 ? xa : (q == 1 ? xb : (q == 2 ? xc : xd));
                    float x0 = h2f((unsigned short)xv);
                    float x1 = h2f((unsigned short)(xv >> 16));
                    float c0 = s_alpha[i + q][0], c1 = s_alpha[i + q][1], c2 = s_alpha[i + q][2];
                    a00 = fmaf(c0, x0, a00); a01 = fmaf(c0, x1, a01);
                    a10 = fmaf(c1, x0, a10); a11 = fmaf(c1, x1, a11);
                    a20 = fmaf(c2, x0, a20); a21 = fmaf(c2, x1, a21);
                }
            }
            for (; i < deg; i++) {
                int sq = s_src[i];
                unsigned int xv = *(const unsigned int*)(x + (size_t)sq * NINP + xoff);
                float x0 = h2f((unsigned short)xv);
                float x1 = h2f((unsigned short)(xv >> 16));
                float c0 = s_alpha[i][0], c1 = s_alpha[i][1], c2 = s_alpha[i][2];
                a00 = fmaf(c0, x0, a00); a01 = fmaf(c0, x1, a01);
                a10 = fmaf(c1, x0, a10); a11 = fmaf(c1, x1, a11);
                a20 = fmaf(c2, x0, a20); a21 = fmaf(c2, x1, a21);
            }
        } else {
            // ---- fallback: 3-pass chunked (deg > 256; rare) ----
            float m0 = -1e30f, m1 = -1e30f, m2 = -1e30f;
            for (int i = t; i < deg; i += 256) {
                int e = eidx[beg + i]; int s = src[e];
                m0 = fmaxf(m0, lrelu(el[s * NH + 0] + er0));
                m1 = fmaxf(m1, lrelu(el[s * NH + 1] + er1));
                m2 = fmaxf(m2, lrelu(el[s * NH + 2] + er2));
            }
            for (int o = 32; o > 0; o >>= 1) {
                m0 = fmaxf(m0, __shfl_xor(m0, o));
                m1 = fmaxf(m1, __shfl_xor(m1, o));
                m2 = fmaxf(m2, __shfl_xor(m2, o));
            }
            if ((t & 63) == 0) { int wv = t >> 6; s_red[wv][0] = m0; s_red[wv][1] = m1; s_red[wv][2] = m2; }
            __syncthreads();
            m0 = fmaxf(fmaxf(s_red[0][0], s_red[1][0]), fmaxf(s_red[2][0], s_red[3][0]));
            m1 = fmaxf(fmaxf(s_red[0][1], s_red[1][1]), fmaxf(s_red[2][1], s_red[3][1]));
            m2 = fmaxf(fmaxf(s_red[0][2], s_red[1][2]), fmaxf(s_red[2][2], s_red[3][2]));
            __syncthreads();
            float z0 = 0.f, z1 = 0.f, z2 = 0.f;
            for (int i = t; i < deg; i += 256) {
                int e = eidx[beg + i]; int s = src[e];
                z0 += expf(lrelu(el[s * NH + 0] + er0) - m0);
                z1 += expf(lrelu(el[s * NH + 1] + er1) - m1);
                z2 += expf(lrelu(el[s * NH + 2] + er2) - m2);
            }
            for (int o = 32; o > 0; o >>= 1) {
                z0 += __shfl_xor(z0, o); z1 += __shfl_xor(z1, o); z2 += __shfl_xor(z2, o);
            }
            if ((t & 63) == 0) { int wv = t >> 6; s_red[wv][0] = z0; s_red[wv][1] = z1; s_red[wv][2] = z2; }
            __syncthreads();
            z0 = s_red[0][0] + s_red[1][0] + s_red[2][0] + s_red[3][0];
            z1 = s_red[0][1] + s_red[1][1] + s_red[2][1] + s_red[3][1];
            z2 = s_red[0][2] + s_red[1][2] + s_red[2][2] + s_red[3][2];
            __syncthreads();
            const float inv0 = 1.0f / z0, inv1 = 1.0f / z1, inv2 = 1.0f / z2;
            for (int base = 0; base < deg; base += MAXC) {
                int cn = min(MAXC, deg - base);
                for (int i = t; i < cn; i += 256) {
                    int e = eidx[beg + base + i]; int s = src[e];
                    s_alpha[i][0] = expf(lrelu(el[s * NH + 0] + er0) - m0) * inv0;
                    s_alpha[i][1] = expf(lrelu(el[s * NH + 1] + er1) - m1) * inv1;
                    s_alpha[i][2] = expf(lrelu(el[s * NH + 2] + er2) - m2) * inv2;
                    s_src[i] = s;
                }
                __syncthreads();
                for (int i = 0; i < cn; i++) {
                    int sq = s_src[i];
                    unsigned int xv = *(const unsigned int*)(x + (size_t)sq * NINP + xoff);
                    float x0 = h2f((unsigned short)xv);
                    float x1 = h2f((unsigned short)(xv >> 16));
                    float c0 = s_alpha[i][0], c1 = s_alpha[i][1], c2 = s_alpha[i][2];
                    a00 = fmaf(c0, x0, a00); a01 = fmaf(c0, x1, a01);
                    a10 = fmaf(c1, x0, a10); a11 = fmaf(c1, x1, a11);
                    a20 = fmaf(c2, x0, a20); a21 = fmaf(c2, x1, a21);
                }
                __syncthreads();
            }
        }
    }

    size_t b = (size_t)n * (NH * NINP) + xoff;
    *(unsigned int*)(agg + b) = (unsigned int)f2h(a00) | ((unsigned int)f2h(a01) << 16);
    *(unsigned int*)(agg + b + NINP) = (unsigned int)f2h(a10) | ((unsigned int)f2h(a11) << 16);
    *(unsigned int*)(agg + b + 2 * NINP) = (unsigned int)f2h(a20) | ((unsigned int)f2h(a21) << 16);
}

// ---------------------------------------------------------------------------
// Single-pass fp16 MFMA GEMM: C[M,N] = A[M,K] @ B[N,K]^T + (deg>0?biasD:bias0)
// 128x128 tile, 4 waves, 4x4 frags of mfma_f32_16x16x32_f16, double-buffered.
// Chunk swizzle c ^= (r>>1)&3 (conflict-free, measured 0 in R3) via
// pre-swizzled global src; bijective XCD-chunked block swizzle.
// ---------------------------------------------------------------------------
template<int K>
__global__ __launch_bounds__(256)
void hgemm_f16(const unsigned short* __restrict__ A, const unsigned short* __restrict__ B,
               const float* __restrict__ biasD, const float* __restrict__ bias0,
               const int* __restrict__ rowptr,
               float* __restrict__ C, int M, int N)
{
    __shared__ __align__(16) unsigned short sA[2][4096];  // [buf][128*32] f16
    __shared__ __align__(16) unsigned short sB[2][4096];

    const int nwg = gridDim.x * gridDim.y;
    int flat = blockIdx.y * gridDim.x + blockIdx.x;
    {
        const int q = nwg >> 3, rr = nwg & 7;
        int xcd = flat & 7, idx = flat >> 3;
        flat = (xcd < rr) ? (xcd * (q + 1) + idx)
                          : (rr * (q + 1) + (xcd - rr) * q + idx);
    }
    const int row0 = (flat / gridDim.x) * 128;
    const int col0 = (flat % gridDim.x) * 128;

    const int tid  = threadIdx.x;
    const int lane = tid & 63;
    const int w    = tid >> 6;
    const int wr   = w >> 1, wc = w & 1;

    // staging: wave w covers 16B-chunks i = w*128 + {0,64} + lane
    int i0 = w * 128 + lane;
    int r0s = i0 >> 2, c0s = i0 & 3;
    int i1 = i0 + 64;
    int r1s = i1 >> 2, c1s = i1 & 3;
    int ar0 = row0 + r0s; if (ar0 >= M) ar0 = M - 1;
    int ar1 = row0 + r1s; if (ar1 >= M) ar1 = M - 1;
    const size_t offA0 = (size_t)ar0 * K + (size_t)((c0s ^ ((r0s >> 1) & 3)) * 8);
    const size_t offA1 = (size_t)ar1 * K + (size_t)((c1s ^ ((r1s >> 1) & 3)) * 8);
    const size_t offB0 = (size_t)(col0 + r0s) * K + (size_t)((c0s ^ ((r0s >> 1) & 3)) * 8);
    const size_t offB1 = (size_t)(col0 + r1s) * K + (size_t)((c1s ^ ((r1s >> 1) & 3)) * 8);
    const int d0 = w * 1024;       // wave-uniform LDS base (f16 units)
    const int d1 = d0 + 512;

    const int fg = lane >> 4, fr = lane & 15;
    int aoff[4], boff[4];
#pragma unroll
    for (int mi = 0; mi < 4; mi++) {
        int r = wr * 64 + mi * 16 + fr;
        aoff[mi] = r * 32 + ((fg ^ ((r >> 1) & 3)) * 8);
    }
#pragma unroll
    for (int ni = 0; ni < 4; ni++) {
        int r = wc * 64 + ni * 16 + fr;
        boff[ni] = r * 32 + ((fg ^ ((r >> 1) & 3)) * 8);
    }

    auto STAGE = [&](int bf, int kof) {
        gload16(A + offA0 + kof, &sA[bf][d0]);
        gload16(A + offA1 + kof, &sA[bf][d1]);
        gload16(B + offB0 + kof, &sB[bf][d0]);
        gload16(B + offB1 + kof, &sB[bf][d1]);
    };

    f32x4 acc[4][4];
#pragma unroll
    for (int mi = 0; mi < 4; mi++)
#pragma unroll
        for (int ni = 0; ni < 4; ni++)
            acc[mi][ni] = (f32x4){0.f, 0.f, 0.f, 0.f};

    const int NT = K / 32;
    STAGE(0, 0);
    __syncthreads();
    for (int kt = 0; kt < NT; kt++) {
        const int cur = kt & 1;
        if (kt + 1 < NT) STAGE(cur ^ 1, (kt + 1) * 32);

        f16x8 a[4], b[4];
#pragma unroll
        for (int mi = 0; mi < 4; mi++) a[mi] = *(const f16x8*)&sA[cur][aoff[mi]];
#pragma unroll
        for (int ni = 0; ni < 4; ni++) b[ni] = *(const f16x8*)&sB[cur][boff[ni]];
#pragma unroll
        for (int mi = 0; mi < 4; mi++)
#pragma unroll
            for (int ni = 0; ni < 4; ni++)
                acc[mi][ni] = __builtin_amdgcn_mfma_f32_16x16x32_f16(a[mi], b[ni], acc[mi][ni], 0, 0, 0);
        __syncthreads();
    }

    // epilogue: C/D layout col=lane&15, row=(lane>>4)*4+reg
#pragma unroll
    for (int mi = 0; mi < 4; mi++) {
        int rb = row0 + wr * 64 + mi * 16 + fg * 4;
        bool dpos[4];
#pragma unroll
        for (int j = 0; j < 4; j++) {
            int r = rb + j;
            dpos[j] = (r < M) ? (rowptr[r + 1] > rowptr[r]) : false;
        }
#pragma unroll
        for (int ni = 0; ni < 4; ni++) {
            int col = col0 + wc * 64 + ni * 16 + fr;
            float bD = biasD[col], b0v = bias0[col];
#pragma unroll
            for (int j = 0; j < 4; j++) {
                int r = rb + j;
                if (r < M)
                    C[(size_t)r * N + col] = acc[mi][ni][j] + (dpos[j] ? bD : b0v);
            }
        }
    }
}

// ---------------------------------------------------------------------------
extern "C" void kernel_launch(void* const* d_in, const int* in_sizes, int n_in,
                              void* d_out, int out_size, void* d_ws, size_t ws_size,
                              hipStream_t stream)
{
    const float* emb_api  = (const float*)d_in[0];
    const float* emb_file = (const float*)d_in[1];
    // d_in[2] (e_tensor) unused by the reference
    const int*   src      = (const int*)d_in[3];
    const int*   dst      = (const int*)d_in[4];
    const float* Wapi     = (const float*)d_in[5];
    const float* bapi     = (const float*)d_in[6];
    const float* Wfile    = (const float*)d_in[7];
    const float* bfile    = (const float*)d_in[8];
    const float* Wsrc     = (const float*)d_in[9];
    const float* Wdst     = (const float*)d_in[10];
    const float* attn_l   = (const float*)d_in[11];
    const float* attn_r   = (const float*)d_in[12];
    const float* gat_bias = (const float*)d_in[13];
    const float* Whead    = (const float*)d_in[14];
    const float* bhead    = (const float*)d_in[15];

    const int n_api  = in_sizes[0] / NINP;   // 50000
    const int n_file = in_sizes[1] / NINP;   // 20000
    const int E      = in_sizes[2];          // 250000

    // ---- workspace carve-up ----
    char* p = (char*)d_ws;
    auto alloc = [&](size_t bytes) -> void* {
        void* r = (void*)p;
        p += (bytes + 255) & ~(size_t)255;
        return r;
    };

    unsigned short* Af16 = (unsigned short*)alloc((size_t)n_api * NINP * 2);       // 51.2 MB
    unsigned short* agg  = (unsigned short*)alloc((size_t)n_file * NH * NINP * 2); // 61.4 MB
    unsigned short* WfT  = (unsigned short*)alloc((size_t)NOUT * NH * NINP * 2);   // 786 KB
    float* el    = (float*)alloc((size_t)n_api  * NH * 4);
    float* er    = (float*)alloc((size_t)n_file * NH * 4);
    float* Wl2   = (float*)alloc((size_t)NINP * NH * 4);
    float* Wr2   = (float*)alloc((size_t)NINP * NH * 4);
    float* elc   = (float*)alloc(16);
    float* erc   = (float*)alloc(16);
    float* bias0 = (float*)alloc((size_t)NOUT * 4);
    float* biasD = (float*)alloc((size_t)NOUT * 4);
    int* cnt    = (int*)alloc((size_t)n_file * 4);
    int* rowptr = (int*)alloc((size_t)(n_file + 1) * 4);
    int* cursor = (int*)alloc((size_t)n_file * 4);
    int* eidx   = (int*)alloc((size_t)E * 4);

    float* out = (float*)d_out;

    // 1) all weight prep + cnt zeroing (one kernel)
    make_weights<<<dim3(MW_GRID), 256, 0, stream>>>(
        Wsrc, Wdst, attn_l, attn_r, Wapi, Wfile, bapi, bfile,
        Whead, gat_bias, bhead, WfT, Wl2, Wr2, elc, erc, bias0, biasD,
        cnt, n_file);

    // 2) node logits + fp16 emb copy + degree count (one kernel)
    const int ncb = (E + 255) / 256;
    node_el_both<<<dim3(NBA + NBF + ncb), 256, 0, stream>>>(
        emb_api, emb_file, Wl2, Wr2, elc, erc, Af16, el, er,
        n_api, n_file, dst, cnt, E);

    // 3) CSR scan + fill
    scan_deg<<<1, 1024, 0, stream>>>(cnt, rowptr, cursor, n_file);
    fill_csr<<<dim3(ncb), 256, 0, stream>>>(dst, cursor, eidx, E);

    // 4) edge softmax + aggregation (fp16 gather, fp32 accum, fp16 agg out)
    gat_agg<<<dim3(n_file), 256, 0, stream>>>(rowptr, eidx, src, el, er, Af16, agg);

    // 5) z = agg[20000,1536] @ Wfull[1536,256]^T + bias(deg)
    hgemm_f16<NH * NINP><<<dim3(NOUT / 128, (n_file + 127) / 128), 256, 0, stream>>>(
        agg, WfT, biasD, bias0, rowptr, out, n_file, NOUT);
}